// Round 1
// baseline (1408.776 us; speedup 1.0000x reference)
//
#include <hip/hip_runtime.h>
#include <hip/hip_bf16.h>
#include <cstdint>
#include <cstddef>

#define NNODES 100000
#define NEDGES 1600000
#define NCLS 40

// ---------------- edge dtype detect + convert ----------------
// If edge_index was serialized as int64 (values < 2^17), every odd 32-bit word
// of the buffer is 0. With int32 random values in [0,1e5) that is impossible.
__global__ void k_detect(const int* __restrict__ ei, int* __restrict__ flag) {
    if (threadIdx.x == 0 && blockIdx.x == 0) {
        int nz = 0;
        for (int i = 1; i < 256; i += 2) nz |= ei[i];
        *flag = (nz == 0) ? 1 : 0;   // 1 => int64 layout
    }
}

__global__ __launch_bounds__(256) void k_convert_count(const int* __restrict__ ei,
        const int* __restrict__ flag, int* __restrict__ src, int* __restrict__ dst,
        int* __restrict__ cnt) {
    int e = blockIdx.x * 256 + threadIdx.x;
    if (e >= NEDGES) return;
    int s, d;
    if (*flag) { s = ei[2 * (size_t)e]; d = ei[2 * ((size_t)NEDGES + e)]; }
    else       { s = ei[e];             d = ei[NEDGES + e]; }
    src[e] = s; dst[e] = d;
    atomicAdd(&cnt[d], 1);
}

__global__ __launch_bounds__(256) void k_dinv(const int* __restrict__ cnt, float* __restrict__ dinv) {
    int i = blockIdx.x * 256 + threadIdx.x;
    if (i < NNODES) dinv[i] = rsqrtf((float)(cnt[i] + 1));   // +1 self-loop
}

// single-block 1024-thread scan over 100k counts -> exclusive offsets
__global__ __launch_bounds__(1024) void k_scan(const int* __restrict__ cnt, int* __restrict__ offs) {
    __shared__ int sm[1024];
    const int t = threadIdx.x;
    int run = 0;
    if (t == 0) offs[0] = 0;
    for (int base = 0; base < NNODES; base += 1024) {
        int idx = base + t;
        int v = (idx < NNODES) ? cnt[idx] : 0;
        sm[t] = v;
        __syncthreads();
        for (int d = 1; d < 1024; d <<= 1) {
            int x = 0;
            if (t >= d) x = sm[t - d];
            __syncthreads();
            sm[t] += x;
            __syncthreads();
        }
        if (idx < NNODES) offs[idx + 1] = run + sm[t];
        run += sm[1023];
        __syncthreads();
    }
}

__global__ __launch_bounds__(256) void k_fill(const int* __restrict__ src, const int* __restrict__ dst,
        const int* __restrict__ offs, int* __restrict__ cursor, int* __restrict__ esrc) {
    int e = blockIdx.x * 256 + threadIdx.x;
    if (e >= NEDGES) return;
    int d = dst[e];
    int pos = offs[d] + atomicAdd(&cursor[d], 1);
    esrc[pos] = src[e];
}

// ---------------- fp32 GEMM: C[M,256] = A[M,256] * B[256,256] ----------------
__global__ __launch_bounds__(256) void gemm128(const float* __restrict__ A, const float* __restrict__ B,
        float* __restrict__ C, int M) {
    __shared__ float As[16][132];   // [k][m] transposed
    __shared__ float Bs[16][132];   // [k][n]
    const int t  = threadIdx.x;
    const int bm = blockIdx.x * 128;
    const int bn = blockIdx.y * 128;
    const int tx = t & 15, ty = t >> 4;
    const int ar = t >> 2, ac = (t & 3) << 2;    // A load: row ar(+64), cols ac..ac+3
    const int br = t >> 5, bc = (t & 31) << 2;   // B load: krow br(+8), cols bc..bc+3
    float acc[8][8];
#pragma unroll
    for (int i = 0; i < 8; ++i)
#pragma unroll
        for (int j = 0; j < 8; ++j) acc[i][j] = 0.f;

    for (int k0 = 0; k0 < 256; k0 += 16) {
        float4 av0 = make_float4(0, 0, 0, 0), av1 = make_float4(0, 0, 0, 0);
        int r0 = bm + ar, r1 = bm + ar + 64;
        if (r0 < M) av0 = *(const float4*)(A + (size_t)r0 * 256 + k0 + ac);
        if (r1 < M) av1 = *(const float4*)(A + (size_t)r1 * 256 + k0 + ac);
        float4 bv0 = *(const float4*)(B + (size_t)(k0 + br) * 256 + bn + bc);
        float4 bv1 = *(const float4*)(B + (size_t)(k0 + br + 8) * 256 + bn + bc);
        __syncthreads();
        As[ac + 0][ar] = av0.x; As[ac + 1][ar] = av0.y; As[ac + 2][ar] = av0.z; As[ac + 3][ar] = av0.w;
        As[ac + 0][ar + 64] = av1.x; As[ac + 1][ar + 64] = av1.y; As[ac + 2][ar + 64] = av1.z; As[ac + 3][ar + 64] = av1.w;
        *(float4*)&Bs[br][bc] = bv0;
        *(float4*)&Bs[br + 8][bc] = bv1;
        __syncthreads();
#pragma unroll
        for (int kk = 0; kk < 16; ++kk) {
            float a[8], b[8];
            *(float4*)&a[0] = *(const float4*)&As[kk][ty * 8];
            *(float4*)&a[4] = *(const float4*)&As[kk][ty * 8 + 4];
            *(float4*)&b[0] = *(const float4*)&Bs[kk][tx * 8];
            *(float4*)&b[4] = *(const float4*)&Bs[kk][tx * 8 + 4];
#pragma unroll
            for (int i = 0; i < 8; ++i)
#pragma unroll
                for (int j = 0; j < 8; ++j)
                    acc[i][j] = fmaf(a[i], b[j], acc[i][j]);
        }
    }
#pragma unroll
    for (int i = 0; i < 8; ++i) {
        int row = bm + ty * 8 + i;
        if (row < M) {
            float* cp = C + (size_t)row * 256 + bn + tx * 8;
            *(float4*)cp       = make_float4(acc[i][0], acc[i][1], acc[i][2], acc[i][3]);
            *(float4*)(cp + 4) = make_float4(acc[i][4], acc[i][5], acc[i][6], acc[i][7]);
        }
    }
}

// ---------------- fp32 GEMM: C[M,40] = A[M,256] * B[256,40] ----------------
__global__ __launch_bounds__(256) void gemm40(const float* __restrict__ A, const float* __restrict__ B,
        float* __restrict__ C, int M) {
    __shared__ float As[16][68];   // [k][m], BM=64
    __shared__ float Bs[16][44];   // [k][n], BN=40
    const int t  = threadIdx.x;
    const int bm = blockIdx.x * 64;
    const int tx = t & 7;          // cols tx*5 .. +4
    const int ty = t >> 3;         // rows ty*2 .. +1
    const int ar = t >> 2, ac = (t & 3) << 2;
    float acc[2][5] = {};
    for (int k0 = 0; k0 < 256; k0 += 16) {
        float4 av = make_float4(0, 0, 0, 0);
        int r0 = bm + ar;
        if (r0 < M) av = *(const float4*)(A + (size_t)r0 * 256 + k0 + ac);
        float4 bv = make_float4(0, 0, 0, 0);
        int brow = t / 10, bcol = (t % 10) * 4;
        if (t < 160) bv = *(const float4*)(B + (size_t)(k0 + brow) * 40 + bcol);
        __syncthreads();
        As[ac + 0][ar] = av.x; As[ac + 1][ar] = av.y; As[ac + 2][ar] = av.z; As[ac + 3][ar] = av.w;
        if (t < 160) {
            Bs[brow][bcol] = bv.x; Bs[brow][bcol + 1] = bv.y;
            Bs[brow][bcol + 2] = bv.z; Bs[brow][bcol + 3] = bv.w;
        }
        __syncthreads();
#pragma unroll
        for (int kk = 0; kk < 16; ++kk) {
            float a0 = As[kk][ty * 2], a1 = As[kk][ty * 2 + 1];
            float b[5];
#pragma unroll
            for (int j = 0; j < 5; ++j) b[j] = Bs[kk][tx * 5 + j];
#pragma unroll
            for (int j = 0; j < 5; ++j) {
                acc[0][j] = fmaf(a0, b[j], acc[0][j]);
                acc[1][j] = fmaf(a1, b[j], acc[1][j]);
            }
        }
    }
#pragma unroll
    for (int i = 0; i < 2; ++i) {
        int row = bm + ty * 2 + i;
        if (row < M) {
#pragma unroll
            for (int j = 0; j < 5; ++j) C[(size_t)row * 40 + tx * 5 + j] = acc[i][j];
        }
    }
}

// ---------------- aggregation: out[i,:] = sum_e norm * T[src,:] (+bias, relu) ----------------
__global__ __launch_bounds__(256) void agg_wide(const float* __restrict__ T, const int* __restrict__ esrc,
        const int* __restrict__ offs, const float* __restrict__ dinv, const float* __restrict__ bias,
        float* __restrict__ out, int relu) {
    int node = blockIdx.x * 4 + (threadIdx.x >> 6);
    int lane = threadIdx.x & 63;
    if (node >= NNODES) return;
    const float4* Tv = (const float4*)T;
    float di = dinv[node];
    float4 v = Tv[(size_t)node * 64 + lane];
    float w = di * di;
    float ax = v.x * w, ay = v.y * w, az = v.z * w, aw = v.w * w;
    int e = offs[node], e1 = offs[node + 1];
    for (; e < e1; ++e) {
        int s = esrc[e];
        float ws = dinv[s] * di;
        float4 u = Tv[(size_t)s * 64 + lane];
        ax = fmaf(u.x, ws, ax); ay = fmaf(u.y, ws, ay);
        az = fmaf(u.z, ws, az); aw = fmaf(u.w, ws, aw);
    }
    float4 bv = ((const float4*)bias)[lane];
    ax += bv.x; ay += bv.y; az += bv.z; aw += bv.w;
    if (relu) {
        ax = fmaxf(ax, 0.f); ay = fmaxf(ay, 0.f);
        az = fmaxf(az, 0.f); aw = fmaxf(aw, 0.f);
    }
    ((float4*)out)[(size_t)node * 64 + lane] = make_float4(ax, ay, az, aw);
}

__global__ __launch_bounds__(256) void agg_out(const float* __restrict__ T, const int* __restrict__ esrc,
        const int* __restrict__ offs, const float* __restrict__ dinv, const float* __restrict__ bias,
        float* __restrict__ out) {
    int node = blockIdx.x * 4 + (threadIdx.x >> 6);
    int lane = threadIdx.x & 63;
    if (node >= NNODES || lane >= NCLS) return;
    float di = dinv[node];
    float acc = di * di * T[(size_t)node * NCLS + lane];
    int e = offs[node], e1 = offs[node + 1];
    for (; e < e1; ++e) {
        int s = esrc[e];
        acc = fmaf(T[(size_t)s * NCLS + lane], dinv[s] * di, acc);
    }
    out[(size_t)node * NCLS + lane] = acc + bias[lane];
}

extern "C" void kernel_launch(void* const* d_in, const int* in_sizes, int n_in,
                              void* d_out, int out_size, void* d_ws, size_t ws_size,
                              hipStream_t stream) {
    const float* x  = (const float*)d_in[0];
    const int*   ei = (const int*)d_in[1];
    const float* W1 = (const float*)d_in[2];
    const float* b1 = (const float*)d_in[3];
    const float* W2 = (const float*)d_in[4];
    const float* b2 = (const float*)d_in[5];
    const float* W3 = (const float*)d_in[6];
    const float* b3 = (const float*)d_in[7];
    float* out = (float*)d_out;

    char* ws = (char*)d_ws;
    size_t o = 0;
    float* bufA  = (float*)(ws + o); o += (size_t)NNODES * 256 * 4;   // 102.4 MB
    float* bufB  = (float*)(ws + o); o += (size_t)NNODES * 256 * 4;   // 102.4 MB
    int* src32   = (int*)(ws + o);   o += (size_t)NEDGES * 4;
    int* dst32   = (int*)(ws + o);   o += (size_t)NEDGES * 4;
    int* esrc    = (int*)(ws + o);   o += (size_t)NEDGES * 4;
    int* cnt     = (int*)(ws + o);   o += 400128;
    int* cursor  = (int*)(ws + o);   o += 400128;
    int* offs    = (int*)(ws + o);   o += 400384;
    float* dinv  = (float*)(ws + o); o += 400128;
    int* flag    = (int*)(ws + o);   o += 256;
    if (ws_size < o) return;   // scratch too small — cannot proceed

    // zero cnt + cursor (contiguous)
    hipMemsetAsync(cnt, 0, 800256, stream);
    k_detect<<<1, 64, 0, stream>>>(ei, flag);
    k_convert_count<<<(NEDGES + 255) / 256, 256, 0, stream>>>(ei, flag, src32, dst32, cnt);
    k_dinv<<<(NNODES + 255) / 256, 256, 0, stream>>>(cnt, dinv);
    k_scan<<<1, 1024, 0, stream>>>(cnt, offs);
    k_fill<<<(NEDGES + 255) / 256, 256, 0, stream>>>(src32, dst32, offs, cursor, esrc);

    dim3 g1((NNODES + 127) / 128, 2), b256(256);
    // layer 1
    gemm128<<<g1, b256, 0, stream>>>(x, W1, bufA, NNODES);
    agg_wide<<<(NNODES + 3) / 4, 256, 0, stream>>>(bufA, esrc, offs, dinv, b1, bufB, 1);
    // layer 2
    gemm128<<<g1, b256, 0, stream>>>(bufB, W2, bufA, NNODES);
    agg_wide<<<(NNODES + 3) / 4, 256, 0, stream>>>(bufA, esrc, offs, dinv, b2, bufB, 1);
    // layer 3
    gemm40<<<(NNODES + 63) / 64, 256, 0, stream>>>(bufB, W3, bufA, NNODES);
    agg_out<<<(NNODES + 3) / 4, 256, 0, stream>>>(bufA, esrc, offs, dinv, b3, out);
}

// Round 2
// 982.774 us; speedup vs baseline: 1.4335x; 1.4335x over previous
//
#include <hip/hip_runtime.h>
#include <hip/hip_bf16.h>
#include <cstdint>
#include <cstddef>

#define NNODES 100000
#define NEDGES 1600000
#define NCLS 40
#define NBLK_SCAN 391   // ceil(100000/256)

// ---- fp16 helpers (clang native _Float16, RNE conversions) ----
__device__ inline float h2f(unsigned short u) {
    _Float16 h; __builtin_memcpy(&h, &u, 2); return (float)h;
}
__device__ inline unsigned short f2h(float f) {
    _Float16 h = (_Float16)f; unsigned short u; __builtin_memcpy(&u, &h, 2); return u;
}

// ---------------- edge dtype detect + convert ----------------
// If edge_index was serialized as int64 (values < 2^17), every odd 32-bit word
// of the buffer is 0. With int32 random values in [0,1e5) that is impossible.
__global__ void k_detect(const int* __restrict__ ei, int* __restrict__ flag) {
    if (threadIdx.x == 0 && blockIdx.x == 0) {
        int nz = 0;
        for (int i = 1; i < 256; i += 2) nz |= ei[i];
        *flag = (nz == 0) ? 1 : 0;   // 1 => int64 layout
    }
}

__global__ __launch_bounds__(256) void k_convert_count(const int* __restrict__ ei,
        const int* __restrict__ flag, int* __restrict__ src, int* __restrict__ dst,
        int* __restrict__ cnt) {
    int e = blockIdx.x * 256 + threadIdx.x;
    if (e >= NEDGES) return;
    int s, d;
    if (*flag) { s = ei[2 * (size_t)e]; d = ei[2 * ((size_t)NEDGES + e)]; }
    else       { s = ei[e];             d = ei[NEDGES + e]; }
    src[e] = s; dst[e] = d;
    atomicAdd(&cnt[d], 1);
}

__global__ __launch_bounds__(256) void k_dinv(const int* __restrict__ cnt, float* __restrict__ dinv) {
    int i = blockIdx.x * 256 + threadIdx.x;
    if (i < NNODES) dinv[i] = rsqrtf((float)(cnt[i] + 1));   // +1 self-loop
}

// ---------------- hierarchical scan: cnt -> offs (exclusive, offs[0]=0) ----------------
__global__ __launch_bounds__(256) void k_scan1(const int* __restrict__ cnt,
        int* __restrict__ incl, int* __restrict__ blksum) {
    __shared__ int sm[256];
    const int t = threadIdx.x;
    int i = blockIdx.x * 256 + t;
    int v = (i < NNODES) ? cnt[i] : 0;
    sm[t] = v;
    __syncthreads();
    for (int d = 1; d < 256; d <<= 1) {
        int x = (t >= d) ? sm[t - d] : 0;
        __syncthreads();
        sm[t] += x;
        __syncthreads();
    }
    if (i < NNODES) incl[i] = sm[t];
    if (t == 255) blksum[blockIdx.x] = sm[255];
}

__global__ __launch_bounds__(512) void k_scan2(const int* __restrict__ blksum, int* __restrict__ blkoff) {
    __shared__ int sm[512];
    const int t = threadIdx.x;
    int v = (t < NBLK_SCAN) ? blksum[t] : 0;
    sm[t] = v;
    __syncthreads();
    for (int d = 1; d < 512; d <<= 1) {
        int x = (t >= d) ? sm[t - d] : 0;
        __syncthreads();
        sm[t] += x;
        __syncthreads();
    }
    if (t < NBLK_SCAN) blkoff[t] = sm[t] - v;   // exclusive
}

__global__ __launch_bounds__(256) void k_scan3(const int* __restrict__ incl,
        const int* __restrict__ blkoff, int* __restrict__ offs) {
    int i = blockIdx.x * 256 + threadIdx.x;
    if (i < NNODES) offs[i + 1] = incl[i] + blkoff[blockIdx.x];
    if (i == 0) offs[0] = 0;
}

__global__ __launch_bounds__(256) void k_fill(const int* __restrict__ src, const int* __restrict__ dst,
        const int* __restrict__ offs, int* __restrict__ cursor, int* __restrict__ esrc) {
    int e = blockIdx.x * 256 + threadIdx.x;
    if (e >= NEDGES) return;
    int d = dst[e];
    int pos = offs[d] + atomicAdd(&cursor[d], 1);
    esrc[pos] = src[e];
}

// ---------------- fp32 GEMM: C[M,256](fp16) = A[M,256] * B[256,256] ----------------
__global__ __launch_bounds__(256) void gemm128_h(const float* __restrict__ A, const float* __restrict__ B,
        unsigned short* __restrict__ C, int M) {
    __shared__ float As[16][132];   // [k][m] transposed
    __shared__ float Bs[16][132];   // [k][n]
    const int t  = threadIdx.x;
    const int bm = blockIdx.x * 128;
    const int bn = blockIdx.y * 128;
    const int tx = t & 15, ty = t >> 4;
    const int ar = t >> 2, ac = (t & 3) << 2;
    const int br = t >> 5, bc = (t & 31) << 2;
    float acc[8][8];
#pragma unroll
    for (int i = 0; i < 8; ++i)
#pragma unroll
        for (int j = 0; j < 8; ++j) acc[i][j] = 0.f;

    for (int k0 = 0; k0 < 256; k0 += 16) {
        float4 av0 = make_float4(0, 0, 0, 0), av1 = make_float4(0, 0, 0, 0);
        int r0 = bm + ar, r1 = bm + ar + 64;
        if (r0 < M) av0 = *(const float4*)(A + (size_t)r0 * 256 + k0 + ac);
        if (r1 < M) av1 = *(const float4*)(A + (size_t)r1 * 256 + k0 + ac);
        float4 bv0 = *(const float4*)(B + (size_t)(k0 + br) * 256 + bn + bc);
        float4 bv1 = *(const float4*)(B + (size_t)(k0 + br + 8) * 256 + bn + bc);
        __syncthreads();
        As[ac + 0][ar] = av0.x; As[ac + 1][ar] = av0.y; As[ac + 2][ar] = av0.z; As[ac + 3][ar] = av0.w;
        As[ac + 0][ar + 64] = av1.x; As[ac + 1][ar + 64] = av1.y; As[ac + 2][ar + 64] = av1.z; As[ac + 3][ar + 64] = av1.w;
        *(float4*)&Bs[br][bc] = bv0;
        *(float4*)&Bs[br + 8][bc] = bv1;
        __syncthreads();
#pragma unroll
        for (int kk = 0; kk < 16; ++kk) {
            float a[8], b[8];
            *(float4*)&a[0] = *(const float4*)&As[kk][ty * 8];
            *(float4*)&a[4] = *(const float4*)&As[kk][ty * 8 + 4];
            *(float4*)&b[0] = *(const float4*)&Bs[kk][tx * 8];
            *(float4*)&b[4] = *(const float4*)&Bs[kk][tx * 8 + 4];
#pragma unroll
            for (int i = 0; i < 8; ++i)
#pragma unroll
                for (int j = 0; j < 8; ++j)
                    acc[i][j] = fmaf(a[i], b[j], acc[i][j]);
        }
    }
#pragma unroll
    for (int i = 0; i < 8; ++i) {
        int row = bm + ty * 8 + i;
        if (row < M) {
            unsigned short* cp = C + (size_t)row * 256 + bn + tx * 8;
            uint4 w;
            w.x = (unsigned)f2h(acc[i][0]) | ((unsigned)f2h(acc[i][1]) << 16);
            w.y = (unsigned)f2h(acc[i][2]) | ((unsigned)f2h(acc[i][3]) << 16);
            w.z = (unsigned)f2h(acc[i][4]) | ((unsigned)f2h(acc[i][5]) << 16);
            w.w = (unsigned)f2h(acc[i][6]) | ((unsigned)f2h(acc[i][7]) << 16);
            *(uint4*)cp = w;
        }
    }
}

// ---------------- fp32 GEMM: C[M,40](fp16) = A[M,256] * B[256,40] ----------------
__global__ __launch_bounds__(256) void gemm40_h(const float* __restrict__ A, const float* __restrict__ B,
        unsigned short* __restrict__ C, int M) {
    __shared__ float As[16][68];   // [k][m], BM=64
    __shared__ float Bs[16][44];   // [k][n], BN=40
    const int t  = threadIdx.x;
    const int bm = blockIdx.x * 64;
    const int tx = t & 7;          // cols tx*5 .. +4
    const int ty = t >> 3;         // rows ty*2 .. +1
    const int ar = t >> 2, ac = (t & 3) << 2;
    float acc[2][5] = {};
    for (int k0 = 0; k0 < 256; k0 += 16) {
        float4 av = make_float4(0, 0, 0, 0);
        int r0 = bm + ar;
        if (r0 < M) av = *(const float4*)(A + (size_t)r0 * 256 + k0 + ac);
        float4 bv = make_float4(0, 0, 0, 0);
        int brow = t / 10, bcol = (t % 10) * 4;
        if (t < 160) bv = *(const float4*)(B + (size_t)(k0 + brow) * 40 + bcol);
        __syncthreads();
        As[ac + 0][ar] = av.x; As[ac + 1][ar] = av.y; As[ac + 2][ar] = av.z; As[ac + 3][ar] = av.w;
        if (t < 160) {
            Bs[brow][bcol] = bv.x; Bs[brow][bcol + 1] = bv.y;
            Bs[brow][bcol + 2] = bv.z; Bs[brow][bcol + 3] = bv.w;
        }
        __syncthreads();
#pragma unroll
        for (int kk = 0; kk < 16; ++kk) {
            float a0 = As[kk][ty * 2], a1 = As[kk][ty * 2 + 1];
            float b[5];
#pragma unroll
            for (int j = 0; j < 5; ++j) b[j] = Bs[kk][tx * 5 + j];
#pragma unroll
            for (int j = 0; j < 5; ++j) {
                acc[0][j] = fmaf(a0, b[j], acc[0][j]);
                acc[1][j] = fmaf(a1, b[j], acc[1][j]);
            }
        }
    }
#pragma unroll
    for (int i = 0; i < 2; ++i) {
        int row = bm + ty * 2 + i;
        if (row < M) {
#pragma unroll
            for (int j = 0; j < 5; ++j) C[(size_t)row * 40 + tx * 5 + j] = f2h(acc[i][j]);
        }
    }
}

// ---------------- aggregation over fp16 table, fp32 accumulate ----------------
__global__ __launch_bounds__(256) void agg_wide_h(const unsigned short* __restrict__ T,
        const int* __restrict__ esrc, const int* __restrict__ offs, const float* __restrict__ dinv,
        const float* __restrict__ bias, float* __restrict__ out, int relu) {
    int node = blockIdx.x * 4 + (threadIdx.x >> 6);
    int lane = threadIdx.x & 63;
    if (node >= NNODES) return;
    const ushort4* Tv = (const ushort4*)T;   // row = 64 x ushort4 (4 feats/lane)
    float di = dinv[node];
    ushort4 v = Tv[(size_t)node * 64 + lane];
    float w = di * di;
    float a0 = h2f(v.x) * w, a1 = h2f(v.y) * w, a2 = h2f(v.z) * w, a3 = h2f(v.w) * w;
    int e = offs[node], e1 = offs[node + 1];
    for (; e + 1 < e1; e += 2) {
        int s0 = esrc[e], s1 = esrc[e + 1];
        ushort4 u0 = Tv[(size_t)s0 * 64 + lane];
        ushort4 u1 = Tv[(size_t)s1 * 64 + lane];
        float w0 = dinv[s0] * di, w1 = dinv[s1] * di;
        a0 = fmaf(h2f(u0.x), w0, a0); a1 = fmaf(h2f(u0.y), w0, a1);
        a2 = fmaf(h2f(u0.z), w0, a2); a3 = fmaf(h2f(u0.w), w0, a3);
        a0 = fmaf(h2f(u1.x), w1, a0); a1 = fmaf(h2f(u1.y), w1, a1);
        a2 = fmaf(h2f(u1.z), w1, a2); a3 = fmaf(h2f(u1.w), w1, a3);
    }
    if (e < e1) {
        int s0 = esrc[e];
        ushort4 u0 = Tv[(size_t)s0 * 64 + lane];
        float w0 = dinv[s0] * di;
        a0 = fmaf(h2f(u0.x), w0, a0); a1 = fmaf(h2f(u0.y), w0, a1);
        a2 = fmaf(h2f(u0.z), w0, a2); a3 = fmaf(h2f(u0.w), w0, a3);
    }
    float4 bv = ((const float4*)bias)[lane];
    a0 += bv.x; a1 += bv.y; a2 += bv.z; a3 += bv.w;
    if (relu) {
        a0 = fmaxf(a0, 0.f); a1 = fmaxf(a1, 0.f);
        a2 = fmaxf(a2, 0.f); a3 = fmaxf(a3, 0.f);
    }
    ((float4*)out)[(size_t)node * 64 + lane] = make_float4(a0, a1, a2, a3);
}

// ---------------- layer-3 aggregation: 40-wide fp16 table -> fp32 out ----------------
__global__ __launch_bounds__(256) void agg_out_h(const unsigned short* __restrict__ T,
        const int* __restrict__ esrc, const int* __restrict__ offs, const float* __restrict__ dinv,
        const float* __restrict__ bias, float* __restrict__ out) {
    int node = blockIdx.x * 4 + (threadIdx.x >> 6);
    int lane = threadIdx.x & 63;
    if (node >= NNODES || lane >= 20) return;   // 20 lanes x 2 classes = 40
    const unsigned* Tv = (const unsigned*)T;    // row = 20 x uint (2 classes each)
    float di = dinv[node];
    float w = di * di;
    unsigned v = Tv[(size_t)node * 20 + lane];
    float a0 = h2f((unsigned short)(v & 0xffff)) * w;
    float a1 = h2f((unsigned short)(v >> 16)) * w;
    int e = offs[node], e1 = offs[node + 1];
    for (; e + 1 < e1; e += 2) {
        int s0 = esrc[e], s1 = esrc[e + 1];
        unsigned u0 = Tv[(size_t)s0 * 20 + lane];
        unsigned u1 = Tv[(size_t)s1 * 20 + lane];
        float w0 = dinv[s0] * di, w1 = dinv[s1] * di;
        a0 = fmaf(h2f((unsigned short)(u0 & 0xffff)), w0, a0);
        a1 = fmaf(h2f((unsigned short)(u0 >> 16)), w0, a1);
        a0 = fmaf(h2f((unsigned short)(u1 & 0xffff)), w1, a0);
        a1 = fmaf(h2f((unsigned short)(u1 >> 16)), w1, a1);
    }
    if (e < e1) {
        int s0 = esrc[e];
        unsigned u0 = Tv[(size_t)s0 * 20 + lane];
        float w0 = dinv[s0] * di;
        a0 = fmaf(h2f((unsigned short)(u0 & 0xffff)), w0, a0);
        a1 = fmaf(h2f((unsigned short)(u0 >> 16)), w0, a1);
    }
    a0 += bias[lane * 2];
    a1 += bias[lane * 2 + 1];
    *(float2*)(out + (size_t)node * 40 + lane * 2) = make_float2(a0, a1);
}

extern "C" void kernel_launch(void* const* d_in, const int* in_sizes, int n_in,
                              void* d_out, int out_size, void* d_ws, size_t ws_size,
                              hipStream_t stream) {
    const float* x  = (const float*)d_in[0];
    const int*   ei = (const int*)d_in[1];
    const float* W1 = (const float*)d_in[2];
    const float* b1 = (const float*)d_in[3];
    const float* W2 = (const float*)d_in[4];
    const float* b2 = (const float*)d_in[5];
    const float* W3 = (const float*)d_in[6];
    const float* b3 = (const float*)d_in[7];
    float* out = (float*)d_out;

    char* ws = (char*)d_ws;
    size_t o = 0;
    unsigned short* tb16 = (unsigned short*)(ws + o); o += (size_t)NNODES * 256 * 2;  // 51.2 MB
    float* hf32  = (float*)(ws + o); o += (size_t)NNODES * 256 * 4;                   // 102.4 MB
    unsigned short* tb40 = (unsigned short*)(ws + o); o += (size_t)NNODES * NCLS * 2; // 8 MB
    int* src32   = (int*)(ws + o);   o += (size_t)NEDGES * 4;
    int* dst32   = (int*)(ws + o);   o += (size_t)NEDGES * 4;
    int* esrc    = (int*)(ws + o);   o += (size_t)NEDGES * 4;
    int* cnt     = (int*)(ws + o);   o += 400128;
    int* cursor  = (int*)(ws + o);   o += 400128;
    int* offs    = (int*)(ws + o);   o += 400384;
    float* dinv  = (float*)(ws + o); o += 400128;
    int* incl    = (int*)(ws + o);   o += 400128;
    int* blksum  = (int*)(ws + o);   o += 2048;
    int* blkoff  = (int*)(ws + o);   o += 2048;
    int* flag    = (int*)(ws + o);   o += 256;
    if (ws_size < o) return;

    hipMemsetAsync(cnt, 0, 800256, stream);   // cnt + cursor contiguous
    k_detect<<<1, 64, 0, stream>>>(ei, flag);
    k_convert_count<<<(NEDGES + 255) / 256, 256, 0, stream>>>(ei, flag, src32, dst32, cnt);
    k_dinv<<<(NNODES + 255) / 256, 256, 0, stream>>>(cnt, dinv);
    k_scan1<<<NBLK_SCAN, 256, 0, stream>>>(cnt, incl, blksum);
    k_scan2<<<1, 512, 0, stream>>>(blksum, blkoff);
    k_scan3<<<NBLK_SCAN, 256, 0, stream>>>(incl, blkoff, offs);
    k_fill<<<(NEDGES + 255) / 256, 256, 0, stream>>>(src32, dst32, offs, cursor, esrc);

    dim3 g1((NNODES + 127) / 128, 2), b256(256);
    // layer 1
    gemm128_h<<<g1, b256, 0, stream>>>(x, W1, tb16, NNODES);
    agg_wide_h<<<(NNODES + 3) / 4, 256, 0, stream>>>(tb16, esrc, offs, dinv, b1, hf32, 1);
    // layer 2
    gemm128_h<<<g1, b256, 0, stream>>>(hf32, W2, tb16, NNODES);
    agg_wide_h<<<(NNODES + 3) / 4, 256, 0, stream>>>(tb16, esrc, offs, dinv, b2, hf32, 1);
    // layer 3
    gemm40_h<<<(NNODES + 63) / 64, 256, 0, stream>>>(hf32, W3, tb40, NNODES);
    agg_out_h<<<(NNODES + 3) / 4, 256, 0, stream>>>(tb40, esrc, offs, dinv, b3, out);
}

// Round 3
// 696.386 us; speedup vs baseline: 2.0230x; 1.4112x over previous
//
#include <hip/hip_runtime.h>
#include <hip/hip_bf16.h>
#include <cstdint>
#include <cstddef>

#define NNODES 100000
#define NEDGES 1600000
#define NCLS 40
#define NBLK_SCAN 391   // ceil(100000/256)
#define MPAD 100096     // 782*128, zero-padded rows

typedef _Float16 f16;
typedef _Float16 f16x8 __attribute__((ext_vector_type(8)));
typedef float f32x4 __attribute__((ext_vector_type(4)));

__device__ inline float h2f(unsigned short u) {
    f16 h; __builtin_memcpy(&h, &u, 2); return (float)h;
}
__device__ inline unsigned short f2h(float f) {
    f16 h = (f16)f; unsigned short u; __builtin_memcpy(&u, &h, 2); return u;
}
__device__ inline void gload_lds16(const void* g, void* l) {
    __builtin_amdgcn_global_load_lds((const __attribute__((address_space(1))) unsigned int*)g,
                                     (__attribute__((address_space(3))) unsigned int*)l, 16, 0, 0);
}

// ---------------- edge dtype detect + convert ----------------
__global__ void k_detect(const int* __restrict__ ei, int* __restrict__ flag) {
    if (threadIdx.x == 0 && blockIdx.x == 0) {
        int nz = 0;
        for (int i = 1; i < 256; i += 2) nz |= ei[i];
        *flag = (nz == 0) ? 1 : 0;   // 1 => int64 layout
    }
}

__global__ __launch_bounds__(256) void k_convert_count(const int* __restrict__ ei,
        const int* __restrict__ flag, int* __restrict__ src, int* __restrict__ dst,
        int* __restrict__ cnt) {
    int e = blockIdx.x * 256 + threadIdx.x;
    if (e >= NEDGES) return;
    int s, d;
    if (*flag) { s = ei[2 * (size_t)e]; d = ei[2 * ((size_t)NEDGES + e)]; }
    else       { s = ei[e];             d = ei[NEDGES + e]; }
    src[e] = s; dst[e] = d;
    atomicAdd(&cnt[d], 1);
}

__global__ __launch_bounds__(256) void k_dinv(const int* __restrict__ cnt, float* __restrict__ dinv) {
    int i = blockIdx.x * 256 + threadIdx.x;
    if (i < NNODES) dinv[i] = rsqrtf((float)(cnt[i] + 1));   // +1 self-loop
}

// ---------------- hierarchical scan ----------------
__global__ __launch_bounds__(256) void k_scan1(const int* __restrict__ cnt,
        int* __restrict__ incl, int* __restrict__ blksum) {
    __shared__ int sm[256];
    const int t = threadIdx.x;
    int i = blockIdx.x * 256 + t;
    int v = (i < NNODES) ? cnt[i] : 0;
    sm[t] = v;
    __syncthreads();
    for (int d = 1; d < 256; d <<= 1) {
        int x = (t >= d) ? sm[t - d] : 0;
        __syncthreads();
        sm[t] += x;
        __syncthreads();
    }
    if (i < NNODES) incl[i] = sm[t];
    if (t == 255) blksum[blockIdx.x] = sm[255];
}

__global__ __launch_bounds__(512) void k_scan2(const int* __restrict__ blksum, int* __restrict__ blkoff) {
    __shared__ int sm[512];
    const int t = threadIdx.x;
    int v = (t < NBLK_SCAN) ? blksum[t] : 0;
    sm[t] = v;
    __syncthreads();
    for (int d = 1; d < 512; d <<= 1) {
        int x = (t >= d) ? sm[t - d] : 0;
        __syncthreads();
        sm[t] += x;
        __syncthreads();
    }
    if (t < NBLK_SCAN) blkoff[t] = sm[t] - v;
}

__global__ __launch_bounds__(256) void k_scan3(const int* __restrict__ incl,
        const int* __restrict__ blkoff, int* __restrict__ offs) {
    int i = blockIdx.x * 256 + threadIdx.x;
    if (i < NNODES) offs[i + 1] = incl[i] + blkoff[blockIdx.x];
    if (i == 0) offs[0] = 0;
}

__global__ __launch_bounds__(256) void k_fill(const int* __restrict__ src, const int* __restrict__ dst,
        const int* __restrict__ offs, int* __restrict__ cursor, int* __restrict__ esrc) {
    int e = blockIdx.x * 256 + threadIdx.x;
    if (e >= NEDGES) return;
    int d = dst[e];
    int pos = offs[d] + atomicAdd(&cursor[d], 1);
    esrc[pos] = src[e];
}

// ---------------- fp32 -> fp16 convert with zero padding ----------------
__global__ __launch_bounds__(256) void k_splitx(const float* __restrict__ x, unsigned short* __restrict__ xh) {
    size_t i = ((size_t)blockIdx.x * 256 + threadIdx.x) * 4;
    if (i >= (size_t)MPAD * 256) return;
    size_t row = i >> 8;
    ushort4 o;
    if (row < NNODES) {
        float4 v = *(const float4*)(x + i);
        o.x = f2h(v.x); o.y = f2h(v.y); o.z = f2h(v.z); o.w = f2h(v.w);
    } else {
        o.x = 0; o.y = 0; o.z = 0; o.w = 0;
    }
    *(ushort4*)(xh + i) = o;
}

// ---------------- W[256][256] fp32 -> WT[n][k] fp16 ----------------
__global__ __launch_bounds__(256) void k_wt(const float* __restrict__ W, unsigned short* __restrict__ WT) {
    int k = blockIdx.x;
    int n = threadIdx.x;
    WT[n * 256 + k] = f2h(W[k * 256 + n]);
}

// ---------------- MFMA fp16 GEMM: C[MPAD,256] = A[MPAD,256] * W, W given as WT[n][k] ----------------
// 128x128 tile, BK=64, 4 waves (2x2 of 64x64), double-buffered LDS, T2 swizzle via
// pre-swizzled global source (slot ^= row&7 within each 128B row), global_load_lds w=16.
__global__ __launch_bounds__(256) void gemm_f16(const unsigned short* __restrict__ A,
        const unsigned short* __restrict__ BT, unsigned short* __restrict__ C) {
    __shared__ __align__(16) char lds[65536];   // 2 bufs x (A 16K + B 16K)
    const int t = threadIdx.x;
    const int w = t >> 6, l = t & 63;
    const int bm = blockIdx.x * 128;
    const int bn = blockIdx.y * 128;
    const int lr = l >> 3, ls = l & 7;

    auto stage = [&](int buf, int k0) {
        char* base = lds + buf * 32768;
#pragma unroll
        for (int i = 0; i < 4; ++i) {
            int r = w * 32 + i * 8 + lr;          // row in tile 0..127
            int sl = ls ^ (r & 7);                // pre-swizzled source slot
            const char* gA = (const char*)A + (size_t)(bm + r) * 512 + (size_t)k0 * 2 + sl * 16;
            gload_lds16(gA, base + (w * 32 + i * 8) * 128);
            const char* gB = (const char*)BT + (size_t)(bn + r) * 512 + (size_t)k0 * 2 + sl * 16;
            gload_lds16(gB, base + 16384 + (w * 32 + i * 8) * 128);
        }
    };

    f32x4 acc[4][4];
#pragma unroll
    for (int m = 0; m < 4; ++m)
#pragma unroll
        for (int n = 0; n < 4; ++n)
            acc[m][n] = (f32x4){0.f, 0.f, 0.f, 0.f};

    const int frow = l & 15, fk = l >> 4;
    const int r0w = (w >> 1) * 64, c0w = (w & 1) * 64;

    stage(0, 0);
    __syncthreads();
    for (int kt = 0; kt < 4; ++kt) {
        const int buf = kt & 1;
        if (kt < 3) stage(buf ^ 1, (kt + 1) * 64);
        const char* As = lds + buf * 32768;
        const char* Bs = As + 16384;
#pragma unroll
        for (int ks = 0; ks < 2; ++ks) {
            f16x8 af[4], bf[4];
#pragma unroll
            for (int m = 0; m < 4; ++m) {
                int ra = r0w + m * 16 + frow;
                af[m] = *(const f16x8*)(As + ra * 128 + (((ks * 4 + fk) ^ (ra & 7)) * 16));
            }
#pragma unroll
            for (int n = 0; n < 4; ++n) {
                int rb = c0w + n * 16 + frow;
                bf[n] = *(const f16x8*)(Bs + rb * 128 + (((ks * 4 + fk) ^ (rb & 7)) * 16));
            }
#pragma unroll
            for (int m = 0; m < 4; ++m)
#pragma unroll
                for (int n = 0; n < 4; ++n)
                    acc[m][n] = __builtin_amdgcn_mfma_f32_16x16x32_f16(af[m], bf[n], acc[m][n], 0, 0, 0);
        }
        __syncthreads();
    }

    // epilogue: repack through LDS (stride 136 u16 to dodge bank conflicts), coalesced fp16 store
    unsigned short* Cs = (unsigned short*)lds;   // [128][136]
    const int crow = (l >> 4) * 4, ccol = l & 15;
#pragma unroll
    for (int m = 0; m < 4; ++m)
#pragma unroll
        for (int n = 0; n < 4; ++n)
#pragma unroll
            for (int r = 0; r < 4; ++r)
                Cs[(r0w + m * 16 + crow + r) * 136 + c0w + n * 16 + ccol] = f2h(acc[m][n][r]);
    __syncthreads();
#pragma unroll
    for (int i = 0; i < 8; ++i) {
        int row = i * 16 + (t >> 4);
        int cs = t & 15;
        uint4 v = *(const uint4*)(Cs + row * 136 + cs * 8);
        *(uint4*)((char*)C + (size_t)(bm + row) * 512 + bn * 2 + cs * 16) = v;
    }
}

// ---------------- fp16-A GEMM: C[M,40](fp16) = A[M,256] * B[256,40] ----------------
__global__ __launch_bounds__(256) void gemm40_h16(const unsigned short* __restrict__ A,
        const float* __restrict__ B, unsigned short* __restrict__ C, int M) {
    __shared__ float As[16][68];
    __shared__ float Bs[16][44];
    const int t  = threadIdx.x;
    const int bm = blockIdx.x * 64;
    const int tx = t & 7;
    const int ty = t >> 3;
    const int ar = t >> 2, ac = (t & 3) << 2;
    float acc[2][5] = {};
    for (int k0 = 0; k0 < 256; k0 += 16) {
        float4 av = make_float4(0, 0, 0, 0);
        int r0 = bm + ar;
        if (r0 < M) {
            ushort4 ah = *(const ushort4*)(A + (size_t)r0 * 256 + k0 + ac);
            av = make_float4(h2f(ah.x), h2f(ah.y), h2f(ah.z), h2f(ah.w));
        }
        float4 bv = make_float4(0, 0, 0, 0);
        int brow = t / 10, bcol = (t % 10) * 4;
        if (t < 160) bv = *(const float4*)(B + (size_t)(k0 + brow) * 40 + bcol);
        __syncthreads();
        As[ac + 0][ar] = av.x; As[ac + 1][ar] = av.y; As[ac + 2][ar] = av.z; As[ac + 3][ar] = av.w;
        if (t < 160) {
            Bs[brow][bcol] = bv.x; Bs[brow][bcol + 1] = bv.y;
            Bs[brow][bcol + 2] = bv.z; Bs[brow][bcol + 3] = bv.w;
        }
        __syncthreads();
#pragma unroll
        for (int kk = 0; kk < 16; ++kk) {
            float a0 = As[kk][ty * 2], a1 = As[kk][ty * 2 + 1];
            float b[5];
#pragma unroll
            for (int j = 0; j < 5; ++j) b[j] = Bs[kk][tx * 5 + j];
#pragma unroll
            for (int j = 0; j < 5; ++j) {
                acc[0][j] = fmaf(a0, b[j], acc[0][j]);
                acc[1][j] = fmaf(a1, b[j], acc[1][j]);
            }
        }
    }
#pragma unroll
    for (int i = 0; i < 2; ++i) {
        int row = bm + ty * 2 + i;
        if (row < M) {
#pragma unroll
            for (int j = 0; j < 5; ++j) C[(size_t)row * 40 + tx * 5 + j] = f2h(acc[i][j]);
        }
    }
}

// ---------------- aggregation: fp16 table in, fp16 out (+bias, relu) ----------------
__global__ __launch_bounds__(256) void agg_wide_hh(const unsigned short* __restrict__ T,
        const int* __restrict__ esrc, const int* __restrict__ offs, const float* __restrict__ dinv,
        const float* __restrict__ bias, unsigned short* __restrict__ outh) {
    int node = blockIdx.x * 4 + (threadIdx.x >> 6);
    int lane = threadIdx.x & 63;
    if (node >= NNODES) return;
    const ushort4* Tv = (const ushort4*)T;
    float di = dinv[node];
    ushort4 v = Tv[(size_t)node * 64 + lane];
    float wself = di * di;
    float a0 = h2f(v.x) * wself, a1 = h2f(v.y) * wself, a2 = h2f(v.z) * wself, a3 = h2f(v.w) * wself;
    int e = offs[node], e1 = offs[node + 1];
    for (; e + 1 < e1; e += 2) {
        int s0 = esrc[e], s1 = esrc[e + 1];
        ushort4 u0 = Tv[(size_t)s0 * 64 + lane];
        ushort4 u1 = Tv[(size_t)s1 * 64 + lane];
        float w0 = dinv[s0] * di, w1 = dinv[s1] * di;
        a0 = fmaf(h2f(u0.x), w0, a0); a1 = fmaf(h2f(u0.y), w0, a1);
        a2 = fmaf(h2f(u0.z), w0, a2); a3 = fmaf(h2f(u0.w), w0, a3);
        a0 = fmaf(h2f(u1.x), w1, a0); a1 = fmaf(h2f(u1.y), w1, a1);
        a2 = fmaf(h2f(u1.z), w1, a2); a3 = fmaf(h2f(u1.w), w1, a3);
    }
    if (e < e1) {
        int s0 = esrc[e];
        ushort4 u0 = Tv[(size_t)s0 * 64 + lane];
        float w0 = dinv[s0] * di;
        a0 = fmaf(h2f(u0.x), w0, a0); a1 = fmaf(h2f(u0.y), w0, a1);
        a2 = fmaf(h2f(u0.z), w0, a2); a3 = fmaf(h2f(u0.w), w0, a3);
    }
    float4 bv = ((const float4*)bias)[lane];
    a0 = fmaxf(a0 + bv.x, 0.f); a1 = fmaxf(a1 + bv.y, 0.f);
    a2 = fmaxf(a2 + bv.z, 0.f); a3 = fmaxf(a3 + bv.w, 0.f);
    ushort4 o; o.x = f2h(a0); o.y = f2h(a1); o.z = f2h(a2); o.w = f2h(a3);
    ((ushort4*)outh)[(size_t)node * 64 + lane] = o;
}

// ---------------- layer-3 aggregation: 40-wide fp16 table -> fp32 out ----------------
__global__ __launch_bounds__(256) void agg_out_h(const unsigned short* __restrict__ T,
        const int* __restrict__ esrc, const int* __restrict__ offs, const float* __restrict__ dinv,
        const float* __restrict__ bias, float* __restrict__ out) {
    int node = blockIdx.x * 4 + (threadIdx.x >> 6);
    int lane = threadIdx.x & 63;
    if (node >= NNODES || lane >= 20) return;   // 20 lanes x 2 classes = 40
    const unsigned* Tv = (const unsigned*)T;
    float di = dinv[node];
    float wself = di * di;
    unsigned v = Tv[(size_t)node * 20 + lane];
    float a0 = h2f((unsigned short)(v & 0xffff)) * wself;
    float a1 = h2f((unsigned short)(v >> 16)) * wself;
    int e = offs[node], e1 = offs[node + 1];
    for (; e + 1 < e1; e += 2) {
        int s0 = esrc[e], s1 = esrc[e + 1];
        unsigned u0 = Tv[(size_t)s0 * 20 + lane];
        unsigned u1 = Tv[(size_t)s1 * 20 + lane];
        float w0 = dinv[s0] * di, w1 = dinv[s1] * di;
        a0 = fmaf(h2f((unsigned short)(u0 & 0xffff)), w0, a0);
        a1 = fmaf(h2f((unsigned short)(u0 >> 16)), w0, a1);
        a0 = fmaf(h2f((unsigned short)(u1 & 0xffff)), w1, a0);
        a1 = fmaf(h2f((unsigned short)(u1 >> 16)), w1, a1);
    }
    if (e < e1) {
        int s0 = esrc[e];
        unsigned u0 = Tv[(size_t)s0 * 20 + lane];
        float w0 = dinv[s0] * di;
        a0 = fmaf(h2f((unsigned short)(u0 & 0xffff)), w0, a0);
        a1 = fmaf(h2f((unsigned short)(u0 >> 16)), w0, a1);
    }
    a0 += bias[lane * 2];
    a1 += bias[lane * 2 + 1];
    *(float2*)(out + (size_t)node * 40 + lane * 2) = make_float2(a0, a1);
}

extern "C" void kernel_launch(void* const* d_in, const int* in_sizes, int n_in,
                              void* d_out, int out_size, void* d_ws, size_t ws_size,
                              hipStream_t stream) {
    const float* x  = (const float*)d_in[0];
    const int*   ei = (const int*)d_in[1];
    const float* W1 = (const float*)d_in[2];
    const float* b1 = (const float*)d_in[3];
    const float* W2 = (const float*)d_in[4];
    const float* b2 = (const float*)d_in[5];
    const float* W3 = (const float*)d_in[6];
    const float* b3 = (const float*)d_in[7];
    float* out = (float*)d_out;

    char* ws = (char*)d_ws;
    size_t o = 0;
    unsigned short* xh   = (unsigned short*)(ws + o); o += (size_t)MPAD * 256 * 2;   // 51.25 MB
    unsigned short* tbA  = (unsigned short*)(ws + o); o += (size_t)MPAD * 256 * 2;   // gemm out
    unsigned short* tbB  = (unsigned short*)(ws + o); o += (size_t)MPAD * 256 * 2;   // agg out
    unsigned short* tb40 = (unsigned short*)(ws + o); o += (size_t)NNODES * NCLS * 2;
    unsigned short* W1T  = (unsigned short*)(ws + o); o += 131072;
    unsigned short* W2T  = (unsigned short*)(ws + o); o += 131072;
    int* src32   = (int*)(ws + o);   o += (size_t)NEDGES * 4;
    int* dst32   = (int*)(ws + o);   o += (size_t)NEDGES * 4;
    int* esrc    = (int*)(ws + o);   o += (size_t)NEDGES * 4;
    int* cnt     = (int*)(ws + o);   o += 400128;
    int* cursor  = (int*)(ws + o);   o += 400128;
    int* offs    = (int*)(ws + o);   o += 400384;
    float* dinv  = (float*)(ws + o); o += 400128;
    int* incl    = (int*)(ws + o);   o += 400128;
    int* blksum  = (int*)(ws + o);   o += 2048;
    int* blkoff  = (int*)(ws + o);   o += 2048;
    int* flag    = (int*)(ws + o);   o += 256;
    if (ws_size < o) return;

    hipMemsetAsync(cnt, 0, 800256, stream);                                   // cnt + cursor
    hipMemsetAsync(tbB + (size_t)NNODES * 256, 0, (MPAD - NNODES) * 512, stream);  // tbB pad rows

    k_detect<<<1, 64, 0, stream>>>(ei, flag);
    k_convert_count<<<(NEDGES + 255) / 256, 256, 0, stream>>>(ei, flag, src32, dst32, cnt);
    k_dinv<<<(NNODES + 255) / 256, 256, 0, stream>>>(cnt, dinv);
    k_scan1<<<NBLK_SCAN, 256, 0, stream>>>(cnt, incl, blksum);
    k_scan2<<<1, 512, 0, stream>>>(blksum, blkoff);
    k_scan3<<<NBLK_SCAN, 256, 0, stream>>>(incl, blkoff, offs);
    k_fill<<<(NEDGES + 255) / 256, 256, 0, stream>>>(src32, dst32, offs, cursor, esrc);

    k_splitx<<<MPAD / 4, 256, 0, stream>>>(x, xh);
    k_wt<<<256, 256, 0, stream>>>(W1, W1T);
    k_wt<<<256, 256, 0, stream>>>(W2, W2T);

    dim3 gg(MPAD / 128, 2), b256(256);
    // layer 1
    gemm_f16<<<gg, b256, 0, stream>>>(xh, W1T, tbA);
    agg_wide_hh<<<(NNODES + 3) / 4, 256, 0, stream>>>(tbA, esrc, offs, dinv, b1, tbB);
    // layer 2
    gemm_f16<<<gg, b256, 0, stream>>>(tbB, W2T, tbA);
    agg_wide_hh<<<(NNODES + 3) / 4, 256, 0, stream>>>(tbA, esrc, offs, dinv, b2, tbB);
    // layer 3
    gemm40_h16<<<(NNODES + 63) / 64, 256, 0, stream>>>(tbB, W3, tb40, NNODES);
    agg_out_h<<<(NNODES + 3) / 4, 256, 0, stream>>>(tb40, esrc, offs, dinv, b3, out);
}

// Round 4
// 664.206 us; speedup vs baseline: 2.1210x; 1.0484x over previous
//
#include <hip/hip_runtime.h>
#include <hip/hip_bf16.h>
#include <cstdint>
#include <cstddef>

#define NNODES 100000
#define NEDGES 1600000
#define NCLS 40
#define NBLK_SCAN 391   // ceil(100000/256)
#define MPAD 100096     // 782*128, zero-padded rows

typedef _Float16 f16;
typedef _Float16 f16x8 __attribute__((ext_vector_type(8)));
typedef float f32x4 __attribute__((ext_vector_type(4)));

__device__ inline float h2f(unsigned short u) {
    f16 h; __builtin_memcpy(&h, &u, 2); return (float)h;
}
__device__ inline unsigned short f2h(float f) {
    f16 h = (f16)f; unsigned short u; __builtin_memcpy(&u, &h, 2); return u;
}
__device__ inline void gload_lds16(const void* g, void* l) {
    __builtin_amdgcn_global_load_lds((const __attribute__((address_space(1))) unsigned int*)g,
                                     (__attribute__((address_space(3))) unsigned int*)l, 16, 0, 0);
}
__device__ inline void acc8(float* a, uint4 v) {
    a[0] += h2f((unsigned short)(v.x & 0xffff)); a[1] += h2f((unsigned short)(v.x >> 16));
    a[2] += h2f((unsigned short)(v.y & 0xffff)); a[3] += h2f((unsigned short)(v.y >> 16));
    a[4] += h2f((unsigned short)(v.z & 0xffff)); a[5] += h2f((unsigned short)(v.z >> 16));
    a[6] += h2f((unsigned short)(v.w & 0xffff)); a[7] += h2f((unsigned short)(v.w >> 16));
}

// ---------------- edge dtype detect + convert ----------------
__global__ void k_detect(const int* __restrict__ ei, int* __restrict__ flag) {
    if (threadIdx.x == 0 && blockIdx.x == 0) {
        int nz = 0;
        for (int i = 1; i < 256; i += 2) nz |= ei[i];
        *flag = (nz == 0) ? 1 : 0;   // 1 => int64 layout
    }
}

__global__ __launch_bounds__(256) void k_convert_count(const int* __restrict__ ei,
        const int* __restrict__ flag, int* __restrict__ src, int* __restrict__ dst,
        int* __restrict__ cnt) {
    int e = blockIdx.x * 256 + threadIdx.x;
    if (e >= NEDGES) return;
    int s, d;
    if (*flag) { s = ei[2 * (size_t)e]; d = ei[2 * ((size_t)NEDGES + e)]; }
    else       { s = ei[e];             d = ei[NEDGES + e]; }
    src[e] = s; dst[e] = d;
    atomicAdd(&cnt[d], 1);
}

// dinv over MPAD (pad rows -> 0)
__global__ __launch_bounds__(256) void k_dinv(const int* __restrict__ cnt, float* __restrict__ dinv) {
    int i = blockIdx.x * 256 + threadIdx.x;
    if (i < MPAD) dinv[i] = (i < NNODES) ? rsqrtf((float)(cnt[i] + 1)) : 0.f;
}

// ---------------- hierarchical scan over (cnt[i]+1)  (self-loop included) ----------------
__global__ __launch_bounds__(256) void k_scan1(const int* __restrict__ cnt,
        int* __restrict__ incl, int* __restrict__ blksum) {
    __shared__ int sm[256];
    const int t = threadIdx.x;
    int i = blockIdx.x * 256 + t;
    int v = (i < NNODES) ? (cnt[i] + 1) : 0;
    sm[t] = v;
    __syncthreads();
    for (int d = 1; d < 256; d <<= 1) {
        int x = (t >= d) ? sm[t - d] : 0;
        __syncthreads();
        sm[t] += x;
        __syncthreads();
    }
    if (i < NNODES) incl[i] = sm[t];
    if (t == 255) blksum[blockIdx.x] = sm[255];
}

__global__ __launch_bounds__(512) void k_scan2(const int* __restrict__ blksum, int* __restrict__ blkoff) {
    __shared__ int sm[512];
    const int t = threadIdx.x;
    int v = (t < NBLK_SCAN) ? blksum[t] : 0;
    sm[t] = v;
    __syncthreads();
    for (int d = 1; d < 512; d <<= 1) {
        int x = (t >= d) ? sm[t - d] : 0;
        __syncthreads();
        sm[t] += x;
        __syncthreads();
    }
    if (t < NBLK_SCAN) blkoff[t] = sm[t] - v;
}

__global__ __launch_bounds__(256) void k_scan3(const int* __restrict__ incl,
        const int* __restrict__ blkoff, int* __restrict__ offs) {
    int i = blockIdx.x * 256 + threadIdx.x;
    if (i < NNODES) offs[i + 1] = incl[i] + blkoff[blockIdx.x];
    if (i == 0) offs[0] = 0;
}

// self edge at slot 0 of each node's bucket; cursor starts at 1
__global__ __launch_bounds__(256) void k_self(const int* __restrict__ offs,
        int* __restrict__ cursor, int* __restrict__ esrc) {
    int i = blockIdx.x * 256 + threadIdx.x;
    if (i < NNODES) { esrc[offs[i]] = i; cursor[i] = 1; }
}

__global__ __launch_bounds__(256) void k_fill(const int* __restrict__ src, const int* __restrict__ dst,
        const int* __restrict__ offs, int* __restrict__ cursor, int* __restrict__ esrc) {
    int e = blockIdx.x * 256 + threadIdx.x;
    if (e >= NEDGES) return;
    int d = dst[e];
    int pos = offs[d] + atomicAdd(&cursor[d], 1);
    esrc[pos] = src[e];
}

// ---------------- W[256][256] fp32 -> WT[n][k] fp16 ----------------
__global__ __launch_bounds__(256) void k_wt(const float* __restrict__ W, unsigned short* __restrict__ WT) {
    int k = blockIdx.x;
    int n = threadIdx.x;
    WT[n * 256 + k] = f2h(W[k * 256 + n]);
}

// ---------------- MFMA fp16 GEMM: C[MPAD,256] = dinv .* (A[MPAD,256] * W), W as WT[n][k] ----------------
// 128x128 tile, BK=64, 4 waves, double-buffered LDS, XOR-swizzled slots.
// A32=true: A is fp32 (reg-staged, cvt to fp16, write-late); else fp16 via global_load_lds.
template<bool A32>
__global__ __launch_bounds__(256) void gemm_core(const void* __restrict__ Ap,
        const unsigned short* __restrict__ BT, unsigned short* __restrict__ C,
        const float* __restrict__ dinv) {
    __shared__ __align__(16) char lds[65536];   // 2 bufs x (A 16K + B 16K)
    const int t = threadIdx.x;
    const int w = t >> 6, l = t & 63;
    const int bm = blockIdx.x * 128;
    const int bn = blockIdx.y * 128;
    const int lr = l >> 3, ls = l & 7;
    const unsigned short* A16 = (const unsigned short*)Ap;
    const float* A32p = (const float*)Ap;

    auto stageB = [&](int buf, int k0) {
        char* base = lds + buf * 32768 + 16384;
#pragma unroll
        for (int i = 0; i < 4; ++i) {
            int r = w * 32 + i * 8 + lr;
            int sl = ls ^ (r & 7);
            const char* gB = (const char*)BT + (size_t)(bn + r) * 512 + (size_t)k0 * 2 + sl * 16;
            gload_lds16(gB, base + (w * 32 + i * 8) * 128);
        }
    };
    auto stageA16 = [&](int buf, int k0) {
        char* base = lds + buf * 32768;
#pragma unroll
        for (int i = 0; i < 4; ++i) {
            int r = w * 32 + i * 8 + lr;
            int sl = ls ^ (r & 7);
            const char* gA = (const char*)A16 + (size_t)(bm + r) * 512 + (size_t)k0 * 2 + sl * 16;
            gload_lds16(gA, base + (w * 32 + i * 8) * 128);
        }
    };
    float4 areg[8];
    auto issueA32 = [&](int k0) {
#pragma unroll
        for (int i = 0; i < 8; ++i) {
            int tt = i * 256 + t;
            int r = tt >> 4, q = tt & 15;
            float4 v = make_float4(0.f, 0.f, 0.f, 0.f);
            if (bm + r < NNODES) v = *(const float4*)(A32p + (size_t)(bm + r) * 256 + k0 + q * 4);
            areg[i] = v;
        }
    };
    auto writeA32 = [&](int buf) {
        char* base = lds + buf * 32768;
#pragma unroll
        for (int i = 0; i < 8; ++i) {
            int tt = i * 256 + t;
            int r = tt >> 4, q = tt & 15;
            f16 h4[4] = {(f16)areg[i].x, (f16)areg[i].y, (f16)areg[i].z, (f16)areg[i].w};
            char* dst = base + r * 128 + (((q >> 1) ^ (r & 7)) * 16) + (q & 1) * 8;
            __builtin_memcpy(dst, h4, 8);   // ds_write_b64
        }
    };

    f32x4 acc[4][4];
#pragma unroll
    for (int m = 0; m < 4; ++m)
#pragma unroll
        for (int n = 0; n < 4; ++n)
            acc[m][n] = (f32x4){0.f, 0.f, 0.f, 0.f};

    const int frow = l & 15, fk = l >> 4;
    const int r0w = (w >> 1) * 64, c0w = (w & 1) * 64;

    if constexpr (A32) { issueA32(0); } else { stageA16(0, 0); }
    stageB(0, 0);
    if constexpr (A32) { writeA32(0); }
    __syncthreads();
    for (int kt = 0; kt < 4; ++kt) {
        const int buf = kt & 1;
        if (kt < 3) {
            if constexpr (A32) { issueA32((kt + 1) * 64); } else { stageA16(buf ^ 1, (kt + 1) * 64); }
            stageB(buf ^ 1, (kt + 1) * 64);
        }
        const char* As = lds + buf * 32768;
        const char* Bs = As + 16384;
#pragma unroll
        for (int ks = 0; ks < 2; ++ks) {
            f16x8 af[4], bf[4];
#pragma unroll
            for (int m = 0; m < 4; ++m) {
                int ra = r0w + m * 16 + frow;
                af[m] = *(const f16x8*)(As + ra * 128 + (((ks * 4 + fk) ^ (ra & 7)) * 16));
            }
#pragma unroll
            for (int n = 0; n < 4; ++n) {
                int rb = c0w + n * 16 + frow;
                bf[n] = *(const f16x8*)(Bs + rb * 128 + (((ks * 4 + fk) ^ (rb & 7)) * 16));
            }
#pragma unroll
            for (int m = 0; m < 4; ++m)
#pragma unroll
                for (int n = 0; n < 4; ++n)
                    acc[m][n] = __builtin_amdgcn_mfma_f32_16x16x32_f16(af[m], bf[n], acc[m][n], 0, 0, 0);
        }
        if constexpr (A32) { if (kt < 3) writeA32(buf ^ 1); }
        __syncthreads();
    }

    // epilogue: scale rows by dinv, repack via LDS (stride 136 u16), coalesced 16B stores
    unsigned short* Cs = (unsigned short*)lds;   // [128][136]
    const int crow = (l >> 4) * 4, ccol = l & 15;
#pragma unroll
    for (int m = 0; m < 4; ++m) {
        float4 dv = *(const float4*)(dinv + bm + r0w + m * 16 + crow);
        float d4[4] = {dv.x, dv.y, dv.z, dv.w};
#pragma unroll
        for (int n = 0; n < 4; ++n)
#pragma unroll
            for (int r = 0; r < 4; ++r)
                Cs[(r0w + m * 16 + crow + r) * 136 + c0w + n * 16 + ccol] = f2h(acc[m][n][r] * d4[r]);
    }
    __syncthreads();
#pragma unroll
    for (int i = 0; i < 8; ++i) {
        int row = i * 16 + (t >> 4);
        int cs = t & 15;
        uint4 v = *(const uint4*)(Cs + row * 136 + cs * 8);
        *(uint4*)((char*)C + (size_t)(bm + row) * 512 + bn * 2 + cs * 16) = v;
    }
}

// ---------------- fp16-A GEMM: C[M,40](fp16, dinv-scaled) = A[M,256] * B[256,40] ----------------
__global__ __launch_bounds__(256) void gemm40_h16(const unsigned short* __restrict__ A,
        const float* __restrict__ B, unsigned short* __restrict__ C, int M,
        const float* __restrict__ dinv) {
    __shared__ float As[16][68];
    __shared__ float Bs[16][44];
    const int t  = threadIdx.x;
    const int bm = blockIdx.x * 64;
    const int tx = t & 7;
    const int ty = t >> 3;
    const int ar = t >> 2, ac = (t & 3) << 2;
    float acc[2][5] = {};
    for (int k0 = 0; k0 < 256; k0 += 16) {
        float4 av = make_float4(0, 0, 0, 0);
        int r0 = bm + ar;
        if (r0 < M) {
            ushort4 ah = *(const ushort4*)(A + (size_t)r0 * 256 + k0 + ac);
            av = make_float4(h2f(ah.x), h2f(ah.y), h2f(ah.z), h2f(ah.w));
        }
        float4 bv = make_float4(0, 0, 0, 0);
        int brow = t / 10, bcol = (t % 10) * 4;
        if (t < 160) bv = *(const float4*)(B + (size_t)(k0 + brow) * 40 + bcol);
        __syncthreads();
        As[ac + 0][ar] = av.x; As[ac + 1][ar] = av.y; As[ac + 2][ar] = av.z; As[ac + 3][ar] = av.w;
        if (t < 160) {
            Bs[brow][bcol] = bv.x; Bs[brow][bcol + 1] = bv.y;
            Bs[brow][bcol + 2] = bv.z; Bs[brow][bcol + 3] = bv.w;
        }
        __syncthreads();
#pragma unroll
        for (int kk = 0; kk < 16; ++kk) {
            float a0 = As[kk][ty * 2], a1 = As[kk][ty * 2 + 1];
            float b[5];
#pragma unroll
            for (int j = 0; j < 5; ++j) b[j] = Bs[kk][tx * 5 + j];
#pragma unroll
            for (int j = 0; j < 5; ++j) {
                acc[0][j] = fmaf(a0, b[j], acc[0][j]);
                acc[1][j] = fmaf(a1, b[j], acc[1][j]);
            }
        }
    }
#pragma unroll
    for (int i = 0; i < 2; ++i) {
        int row = bm + ty * 2 + i;
        if (row < M) {
            float dv = dinv[row];
#pragma unroll
            for (int j = 0; j < 5; ++j) C[(size_t)row * 40 + tx * 5 + j] = f2h(acc[i][j] * dv);
        }
    }
}

// ---------------- aggregation v2: pre-scaled fp16 table, self in CSR ----------------
// wave per node; half-wave (32 lanes x 16B) per edge; unroll 2 -> 4 gathers in flight.
__global__ __launch_bounds__(256) void agg_v2(const unsigned short* __restrict__ T,
        const int* __restrict__ esrc, const int* __restrict__ offs,
        const float* __restrict__ dinv, const float* __restrict__ bias,
        unsigned short* __restrict__ outh) {
    int node = blockIdx.x * 4 + (threadIdx.x >> 6);
    if (node >= NNODES) return;
    const int l = threadIdx.x & 63;
    const int half = l >> 5, sub = l & 31;
    const uint4* Tv = (const uint4*)T;   // row = 32 x uint4
    float a[8] = {0.f, 0.f, 0.f, 0.f, 0.f, 0.f, 0.f, 0.f};
    const int e0 = offs[node], e1 = offs[node + 1];
    int e = e0 + half;
    for (; e + 2 < e1; e += 4) {
        int s0 = esrc[e], s1 = esrc[e + 2];
        uint4 u0 = Tv[(size_t)s0 * 32 + sub];
        uint4 u1 = Tv[(size_t)s1 * 32 + sub];
        acc8(a, u0);
        acc8(a, u1);
    }
    for (; e < e1; e += 2) {
        int s0 = esrc[e];
        uint4 u0 = Tv[(size_t)s0 * 32 + sub];
        acc8(a, u0);
    }
#pragma unroll
    for (int j = 0; j < 8; ++j) a[j] += __shfl_xor(a[j], 32, 64);
    if (!half) {
        float di = dinv[node];
        float4 b0 = *(const float4*)(bias + sub * 8);
        float4 b1 = *(const float4*)(bias + sub * 8 + 4);
        float r0 = fmaxf(fmaf(a[0], di, b0.x), 0.f);
        float r1 = fmaxf(fmaf(a[1], di, b0.y), 0.f);
        float r2 = fmaxf(fmaf(a[2], di, b0.z), 0.f);
        float r3 = fmaxf(fmaf(a[3], di, b0.w), 0.f);
        float r4 = fmaxf(fmaf(a[4], di, b1.x), 0.f);
        float r5 = fmaxf(fmaf(a[5], di, b1.y), 0.f);
        float r6 = fmaxf(fmaf(a[6], di, b1.z), 0.f);
        float r7 = fmaxf(fmaf(a[7], di, b1.w), 0.f);
        uint4 o;
        o.x = (unsigned)f2h(r0) | ((unsigned)f2h(r1) << 16);
        o.y = (unsigned)f2h(r2) | ((unsigned)f2h(r3) << 16);
        o.z = (unsigned)f2h(r4) | ((unsigned)f2h(r5) << 16);
        o.w = (unsigned)f2h(r6) | ((unsigned)f2h(r7) << 16);
        ((uint4*)outh)[(size_t)node * 32 + sub] = o;
    }
}

// ---------------- layer-3 aggregation: 16-lane group per edge, 4 edges/iter ----------------
__global__ __launch_bounds__(256) void agg_out_v2(const unsigned short* __restrict__ T,
        const int* __restrict__ esrc, const int* __restrict__ offs,
        const float* __restrict__ dinv, const float* __restrict__ bias,
        float* __restrict__ out) {
    int node = blockIdx.x * 4 + (threadIdx.x >> 6);
    if (node >= NNODES) return;
    const int l = threadIdx.x & 63;
    const int g = l >> 4, sl = l & 15;
    const bool act = sl < 10;
    float a0 = 0.f, a1 = 0.f, a2 = 0.f, a3 = 0.f;
    const int e0 = offs[node], e1 = offs[node + 1];
    for (int e = e0 + g; e < e1; e += 4) {
        int s = esrc[e];
        if (act) {
            ushort4 u = *(const ushort4*)(T + (size_t)s * 40 + sl * 4);
            a0 += h2f(u.x); a1 += h2f(u.y); a2 += h2f(u.z); a3 += h2f(u.w);
        }
    }
    a0 += __shfl_xor(a0, 16, 64); a1 += __shfl_xor(a1, 16, 64);
    a2 += __shfl_xor(a2, 16, 64); a3 += __shfl_xor(a3, 16, 64);
    a0 += __shfl_xor(a0, 32, 64); a1 += __shfl_xor(a1, 32, 64);
    a2 += __shfl_xor(a2, 32, 64); a3 += __shfl_xor(a3, 32, 64);
    if (g == 0 && act) {
        float di = dinv[node];
        float4 bv = *(const float4*)(bias + sl * 4);
        float4 o = make_float4(fmaf(a0, di, bv.x), fmaf(a1, di, bv.y),
                               fmaf(a2, di, bv.z), fmaf(a3, di, bv.w));
        *(float4*)(out + (size_t)node * 40 + sl * 4) = o;
    }
}

extern "C" void kernel_launch(void* const* d_in, const int* in_sizes, int n_in,
                              void* d_out, int out_size, void* d_ws, size_t ws_size,
                              hipStream_t stream) {
    const float* x  = (const float*)d_in[0];
    const int*   ei = (const int*)d_in[1];
    const float* W1 = (const float*)d_in[2];
    const float* b1 = (const float*)d_in[3];
    const float* W2 = (const float*)d_in[4];
    const float* b2 = (const float*)d_in[5];
    const float* W3 = (const float*)d_in[6];
    const float* b3 = (const float*)d_in[7];
    float* out = (float*)d_out;

    char* ws = (char*)d_ws;
    size_t o = 0;
    unsigned short* tbA  = (unsigned short*)(ws + o); o += (size_t)MPAD * 256 * 2;   // gemm out (dinv-scaled)
    unsigned short* tbB  = (unsigned short*)(ws + o); o += (size_t)MPAD * 256 * 2;   // agg out (h, relu'd)
    unsigned short* tb40 = (unsigned short*)(ws + o); o += (size_t)NNODES * NCLS * 2;
    unsigned short* W1T  = (unsigned short*)(ws + o); o += 131072;
    unsigned short* W2T  = (unsigned short*)(ws + o); o += 131072;
    int* src32   = (int*)(ws + o);   o += (size_t)NEDGES * 4;
    int* dst32   = (int*)(ws + o);   o += (size_t)NEDGES * 4;
    int* esrc    = (int*)(ws + o);   o += (size_t)(NEDGES + NNODES) * 4;
    int* cnt     = (int*)(ws + o);   o += 400128;
    int* cursor  = (int*)(ws + o);   o += 400128;
    int* offs    = (int*)(ws + o);   o += 400384;
    float* dinv  = (float*)(ws + o); o += 400384;   // MPAD entries, pad=0
    int* incl    = (int*)(ws + o);   o += 400128;
    int* blksum  = (int*)(ws + o);   o += 2048;
    int* blkoff  = (int*)(ws + o);   o += 2048;
    int* flag    = (int*)(ws + o);   o += 256;
    if (ws_size < o) return;

    hipMemsetAsync(cnt, 0, 400128, stream);
    hipMemsetAsync(tbB + (size_t)NNODES * 256, 0, (MPAD - NNODES) * 512, stream);  // tbB pad rows

    k_detect<<<1, 64, 0, stream>>>(ei, flag);
    k_convert_count<<<(NEDGES + 255) / 256, 256, 0, stream>>>(ei, flag, src32, dst32, cnt);
    k_dinv<<<(MPAD + 255) / 256, 256, 0, stream>>>(cnt, dinv);
    k_scan1<<<NBLK_SCAN, 256, 0, stream>>>(cnt, incl, blksum);
    k_scan2<<<1, 512, 0, stream>>>(blksum, blkoff);
    k_scan3<<<NBLK_SCAN, 256, 0, stream>>>(incl, blkoff, offs);
    k_self<<<NBLK_SCAN, 256, 0, stream>>>(offs, cursor, esrc);
    k_fill<<<(NEDGES + 255) / 256, 256, 0, stream>>>(src32, dst32, offs, cursor, esrc);

    k_wt<<<256, 256, 0, stream>>>(W1, W1T);
    k_wt<<<256, 256, 0, stream>>>(W2, W2T);

    dim3 gg(MPAD / 128, 2), b256(256);
    // layer 1 (A = fp32 x, read directly)
    gemm_core<true><<<gg, b256, 0, stream>>>(x, W1T, tbA, dinv);
    agg_v2<<<NNODES / 4, 256, 0, stream>>>(tbA, esrc, offs, dinv, b1, tbB);
    // layer 2
    gemm_core<false><<<gg, b256, 0, stream>>>(tbB, W2T, tbA, dinv);
    agg_v2<<<NNODES / 4, 256, 0, stream>>>(tbA, esrc, offs, dinv, b2, tbB);
    // layer 3
    gemm40_h16<<<(NNODES + 63) / 64, 256, 0, stream>>>(tbB, W3, tb40, NNODES, dinv);
    agg_out_v2<<<NNODES / 4, 256, 0, stream>>>(tb40, esrc, offs, dinv, b3, out);
}

// Round 5
// 544.960 us; speedup vs baseline: 2.5851x; 1.2188x over previous
//
#include <hip/hip_runtime.h>
#include <hip/hip_bf16.h>
#include <cstdint>
#include <cstddef>

#define NNODES 100000
#define NEDGES 1600000
#define NCLS 40
#define NBLK_SCAN 391   // ceil(100000/256)
#define NBUCK 391       // dst>>8 buckets (256 nodes each)
#define BCAP 5120       // bucket capacity (mean 4096, +16 sigma)
#define NBLKB 256
#define CHUNK 6250      // NEDGES / NBLKB exactly
#define MPAD 100096     // 782*128, zero-padded rows

typedef _Float16 f16;
typedef _Float16 f16x8 __attribute__((ext_vector_type(8)));
typedef float f32x4 __attribute__((ext_vector_type(4)));

__device__ inline float h2f(unsigned short u) {
    f16 h; __builtin_memcpy(&h, &u, 2); return (float)h;
}
__device__ inline unsigned short f2h(float f) {
    f16 h = (f16)f; unsigned short u; __builtin_memcpy(&u, &h, 2); return u;
}
__device__ inline void gload_lds16(const void* g, void* l) {
    __builtin_amdgcn_global_load_lds((const __attribute__((address_space(1))) unsigned int*)g,
                                     (__attribute__((address_space(3))) unsigned int*)l, 16, 0, 0);
}
__device__ inline void acc8(float* a, uint4 v) {
    a[0] += h2f((unsigned short)(v.x & 0xffff)); a[1] += h2f((unsigned short)(v.x >> 16));
    a[2] += h2f((unsigned short)(v.y & 0xffff)); a[3] += h2f((unsigned short)(v.y >> 16));
    a[4] += h2f((unsigned short)(v.z & 0xffff)); a[5] += h2f((unsigned short)(v.z >> 16));
    a[6] += h2f((unsigned short)(v.w & 0xffff)); a[7] += h2f((unsigned short)(v.w >> 16));
}

// ---------------- edge dtype detect ----------------
__global__ void k_detect(const int* __restrict__ ei, int* __restrict__ flag) {
    if (threadIdx.x == 0 && blockIdx.x == 0) {
        int nz = 0;
        for (int i = 1; i < 256; i += 2) nz |= ei[i];
        *flag = (nz == 0) ? 1 : 0;   // 1 => int64 layout
    }
}

// ---------------- bucketed edge partition (LDS histogram + grouped writes) ----------------
__global__ __launch_bounds__(256) void k_bucket(const int* __restrict__ ei,
        const int* __restrict__ flag, int* __restrict__ gbcnt, int2* __restrict__ bedge) {
    __shared__ int lcnt[NBUCK], lbase[NBUCK], lcur[NBUCK];
    const int t = threadIdx.x;
    const int is64 = *flag;
    for (int i = t; i < NBUCK; i += 256) lcnt[i] = 0;
    __syncthreads();
    const int e0 = blockIdx.x * CHUNK;
    for (int i = t; i < CHUNK; i += 256) {
        int e = e0 + i;
        int d = is64 ? ei[2 * ((size_t)NEDGES + e)] : ei[NEDGES + e];
        atomicAdd(&lcnt[d >> 8], 1);
    }
    __syncthreads();
    for (int i = t; i < NBUCK; i += 256) {
        int c = lcnt[i];
        lbase[i] = c ? atomicAdd(&gbcnt[i], c) : 0;
        lcur[i] = 0;
    }
    __syncthreads();
    for (int i = t; i < CHUNK; i += 256) {
        int e = e0 + i;
        int s, d;
        if (is64) { s = ei[2 * (size_t)e]; d = ei[2 * ((size_t)NEDGES + e)]; }
        else      { s = ei[e];             d = ei[NEDGES + e]; }
        int b = d >> 8;
        int p = lbase[b] + atomicAdd(&lcur[b], 1);
        if (p < BCAP) bedge[(size_t)b * BCAP + p] = make_int2(s, d);
    }
}

// ---------------- per-bucket node-degree count ----------------
__global__ __launch_bounds__(256) void k_cnt(const int* __restrict__ gbcnt,
        const int2* __restrict__ bedge, int* __restrict__ cnt) {
    __shared__ int lc[256];
    const int t = threadIdx.x, b = blockIdx.x;
    lc[t] = 0;
    __syncthreads();
    const int ne = min(gbcnt[b], BCAP);
    const int2* be = bedge + (size_t)b * BCAP;
    for (int i = t; i < ne; i += 256)
        atomicAdd(&lc[be[i].y & 255], 1);
    __syncthreads();
    int node = b * 256 + t;
    if (node < NNODES) cnt[node] = lc[t];
}

// dinv over MPAD (pad rows -> 0)
__global__ __launch_bounds__(256) void k_dinv(const int* __restrict__ cnt, float* __restrict__ dinv) {
    int i = blockIdx.x * 256 + threadIdx.x;
    if (i < MPAD) dinv[i] = (i < NNODES) ? rsqrtf((float)(cnt[i] + 1)) : 0.f;
}

// ---------------- hierarchical scan over (cnt[i]+1)  (self-loop included) ----------------
__global__ __launch_bounds__(256) void k_scan1(const int* __restrict__ cnt,
        int* __restrict__ incl, int* __restrict__ blksum) {
    __shared__ int sm[256];
    const int t = threadIdx.x;
    int i = blockIdx.x * 256 + t;
    int v = (i < NNODES) ? (cnt[i] + 1) : 0;
    sm[t] = v;
    __syncthreads();
    for (int d = 1; d < 256; d <<= 1) {
        int x = (t >= d) ? sm[t - d] : 0;
        __syncthreads();
        sm[t] += x;
        __syncthreads();
    }
    if (i < NNODES) incl[i] = sm[t];
    if (t == 255) blksum[blockIdx.x] = sm[255];
}

__global__ __launch_bounds__(512) void k_scan2(const int* __restrict__ blksum, int* __restrict__ blkoff) {
    __shared__ int sm[512];
    const int t = threadIdx.x;
    int v = (t < NBLK_SCAN) ? blksum[t] : 0;
    sm[t] = v;
    __syncthreads();
    for (int d = 1; d < 512; d <<= 1) {
        int x = (t >= d) ? sm[t - d] : 0;
        __syncthreads();
        sm[t] += x;
        __syncthreads();
    }
    if (t < NBLK_SCAN) blkoff[t] = sm[t] - v;
}

__global__ __launch_bounds__(256) void k_scan3(const int* __restrict__ incl,
        const int* __restrict__ blkoff, int* __restrict__ offs) {
    int i = blockIdx.x * 256 + threadIdx.x;
    if (i < NNODES) offs[i + 1] = incl[i] + blkoff[blockIdx.x];
    if (i == 0) offs[0] = 0;
}

// self edge at slot 0 of each node's bucket
__global__ __launch_bounds__(256) void k_self(const int* __restrict__ offs, int* __restrict__ esrc) {
    int i = blockIdx.x * 256 + threadIdx.x;
    if (i < NNODES) esrc[offs[i]] = i;
}

// ---------------- per-bucket exact scatter (L2-local, block-exclusive region) ----------------
__global__ __launch_bounds__(256) void k_fill2(const int* __restrict__ gbcnt,
        const int2* __restrict__ bedge, const int* __restrict__ offs, int* __restrict__ esrc) {
    __shared__ int loff[256], lcur[256];
    const int t = threadIdx.x, b = blockIdx.x;
    int node = b * 256 + t;
    loff[t] = (node < NNODES) ? offs[node] : 0;
    lcur[t] = 0;
    __syncthreads();
    const int ne = min(gbcnt[b], BCAP);
    const int2* be = bedge + (size_t)b * BCAP;
    for (int i = t; i < ne; i += 256) {
        int2 sd = be[i];
        int li = sd.y & 255;
        int p = loff[li] + 1 + atomicAdd(&lcur[li], 1);   // +1: slot 0 is self-loop
        esrc[p] = sd.x;
    }
}

// ---------------- W[256][256] fp32 -> WT[n][k] fp16 ----------------
__global__ __launch_bounds__(256) void k_wt(const float* __restrict__ W, unsigned short* __restrict__ WT) {
    int k = blockIdx.x;
    int n = threadIdx.x;
    WT[n * 256 + k] = f2h(W[k * 256 + n]);
}

// ---------------- MFMA fp16 GEMM: C[MPAD,256] = dinv .* (A[MPAD,256] * W), W as WT[n][k] ----------------
template<bool A32>
__global__ __launch_bounds__(256) void gemm_core(const void* __restrict__ Ap,
        const unsigned short* __restrict__ BT, unsigned short* __restrict__ C,
        const float* __restrict__ dinv) {
    __shared__ __align__(16) char lds[65536];   // 2 bufs x (A 16K + B 16K)
    const int t = threadIdx.x;
    const int w = t >> 6, l = t & 63;
    const int bm = blockIdx.x * 128;
    const int bn = blockIdx.y * 128;
    const int lr = l >> 3, ls = l & 7;
    const unsigned short* A16 = (const unsigned short*)Ap;
    const float* A32p = (const float*)Ap;

    auto stageB = [&](int buf, int k0) {
        char* base = lds + buf * 32768 + 16384;
#pragma unroll
        for (int i = 0; i < 4; ++i) {
            int r = w * 32 + i * 8 + lr;
            int sl = ls ^ (r & 7);
            const char* gB = (const char*)BT + (size_t)(bn + r) * 512 + (size_t)k0 * 2 + sl * 16;
            gload_lds16(gB, base + (w * 32 + i * 8) * 128);
        }
    };
    auto stageA16 = [&](int buf, int k0) {
        char* base = lds + buf * 32768;
#pragma unroll
        for (int i = 0; i < 4; ++i) {
            int r = w * 32 + i * 8 + lr;
            int sl = ls ^ (r & 7);
            const char* gA = (const char*)A16 + (size_t)(bm + r) * 512 + (size_t)k0 * 2 + sl * 16;
            gload_lds16(gA, base + (w * 32 + i * 8) * 128);
        }
    };
    float4 areg[8];
    auto issueA32 = [&](int k0) {
#pragma unroll
        for (int i = 0; i < 8; ++i) {
            int tt = i * 256 + t;
            int r = tt >> 4, q = tt & 15;
            float4 v = make_float4(0.f, 0.f, 0.f, 0.f);
            if (bm + r < NNODES) v = *(const float4*)(A32p + (size_t)(bm + r) * 256 + k0 + q * 4);
            areg[i] = v;
        }
    };
    auto writeA32 = [&](int buf) {
        char* base = lds + buf * 32768;
#pragma unroll
        for (int i = 0; i < 8; ++i) {
            int tt = i * 256 + t;
            int r = tt >> 4, q = tt & 15;
            f16 h4[4] = {(f16)areg[i].x, (f16)areg[i].y, (f16)areg[i].z, (f16)areg[i].w};
            char* dst = base + r * 128 + (((q >> 1) ^ (r & 7)) * 16) + (q & 1) * 8;
            __builtin_memcpy(dst, h4, 8);   // ds_write_b64
        }
    };

    f32x4 acc[4][4];
#pragma unroll
    for (int m = 0; m < 4; ++m)
#pragma unroll
        for (int n = 0; n < 4; ++n)
            acc[m][n] = (f32x4){0.f, 0.f, 0.f, 0.f};

    const int frow = l & 15, fk = l >> 4;
    const int r0w = (w >> 1) * 64, c0w = (w & 1) * 64;

    if constexpr (A32) { issueA32(0); } else { stageA16(0, 0); }
    stageB(0, 0);
    if constexpr (A32) { writeA32(0); }
    __syncthreads();
    for (int kt = 0; kt < 4; ++kt) {
        const int buf = kt & 1;
        if (kt < 3) {
            if constexpr (A32) { issueA32((kt + 1) * 64); } else { stageA16(buf ^ 1, (kt + 1) * 64); }
            stageB(buf ^ 1, (kt + 1) * 64);
        }
        const char* As = lds + buf * 32768;
        const char* Bs = As + 16384;
#pragma unroll
        for (int ks = 0; ks < 2; ++ks) {
            f16x8 af[4], bf[4];
#pragma unroll
            for (int m = 0; m < 4; ++m) {
                int ra = r0w + m * 16 + frow;
                af[m] = *(const f16x8*)(As + ra * 128 + (((ks * 4 + fk) ^ (ra & 7)) * 16));
            }
#pragma unroll
            for (int n = 0; n < 4; ++n) {
                int rb = c0w + n * 16 + frow;
                bf[n] = *(const f16x8*)(Bs + rb * 128 + (((ks * 4 + fk) ^ (rb & 7)) * 16));
            }
#pragma unroll
            for (int m = 0; m < 4; ++m)
#pragma unroll
                for (int n = 0; n < 4; ++n)
                    acc[m][n] = __builtin_amdgcn_mfma_f32_16x16x32_f16(af[m], bf[n], acc[m][n], 0, 0, 0);
        }
        if constexpr (A32) { if (kt < 3) writeA32(buf ^ 1); }
        __syncthreads();
    }

    // epilogue: scale rows by dinv, repack via LDS (stride 136 u16), coalesced 16B stores
    unsigned short* Cs = (unsigned short*)lds;   // [128][136]
    const int crow = (l >> 4) * 4, ccol = l & 15;
#pragma unroll
    for (int m = 0; m < 4; ++m) {
        float4 dv = *(const float4*)(dinv + bm + r0w + m * 16 + crow);
        float d4[4] = {dv.x, dv.y, dv.z, dv.w};
#pragma unroll
        for (int n = 0; n < 4; ++n)
#pragma unroll
            for (int r = 0; r < 4; ++r)
                Cs[(r0w + m * 16 + crow + r) * 136 + c0w + n * 16 + ccol] = f2h(acc[m][n][r] * d4[r]);
    }
    __syncthreads();
#pragma unroll
    for (int i = 0; i < 8; ++i) {
        int row = i * 16 + (t >> 4);
        int cs = t & 15;
        uint4 v = *(const uint4*)(Cs + row * 136 + cs * 8);
        *(uint4*)((char*)C + (size_t)(bm + row) * 512 + bn * 2 + cs * 16) = v;
    }
}

// ---------------- fp16-A GEMM: C[M,40](fp16, dinv-scaled) = A[M,256] * B[256,40] ----------------
__global__ __launch_bounds__(256) void gemm40_h16(const unsigned short* __restrict__ A,
        const float* __restrict__ B, unsigned short* __restrict__ C, int M,
        const float* __restrict__ dinv) {
    __shared__ float As[16][68];
    __shared__ float Bs[16][44];
    const int t  = threadIdx.x;
    const int bm = blockIdx.x * 64;
    const int tx = t & 7;
    const int ty = t >> 3;
    const int ar = t >> 2, ac = (t & 3) << 2;
    float acc[2][5] = {};
    for (int k0 = 0; k0 < 256; k0 += 16) {
        float4 av = make_float4(0, 0, 0, 0);
        int r0 = bm + ar;
        if (r0 < M) {
            ushort4 ah = *(const ushort4*)(A + (size_t)r0 * 256 + k0 + ac);
            av = make_float4(h2f(ah.x), h2f(ah.y), h2f(ah.z), h2f(ah.w));
        }
        float4 bv = make_float4(0, 0, 0, 0);
        int brow = t / 10, bcol = (t % 10) * 4;
        if (t < 160) bv = *(const float4*)(B + (size_t)(k0 + brow) * 40 + bcol);
        __syncthreads();
        As[ac + 0][ar] = av.x; As[ac + 1][ar] = av.y; As[ac + 2][ar] = av.z; As[ac + 3][ar] = av.w;
        if (t < 160) {
            Bs[brow][bcol] = bv.x; Bs[brow][bcol + 1] = bv.y;
            Bs[brow][bcol + 2] = bv.z; Bs[brow][bcol + 3] = bv.w;
        }
        __syncthreads();
#pragma unroll
        for (int kk = 0; kk < 16; ++kk) {
            float a0 = As[kk][ty * 2], a1 = As[kk][ty * 2 + 1];
            float b[5];
#pragma unroll
            for (int j = 0; j < 5; ++j) b[j] = Bs[kk][tx * 5 + j];
#pragma unroll
            for (int j = 0; j < 5; ++j) {
                acc[0][j] = fmaf(a0, b[j], acc[0][j]);
                acc[1][j] = fmaf(a1, b[j], acc[1][j]);
            }
        }
    }
#pragma unroll
    for (int i = 0; i < 2; ++i) {
        int row = bm + ty * 2 + i;
        if (row < M) {
            float dv = dinv[row];
#pragma unroll
            for (int j = 0; j < 5; ++j) C[(size_t)row * 40 + tx * 5 + j] = f2h(acc[i][j] * dv);
        }
    }
}

// ---------------- aggregation: pre-scaled fp16 table, self in CSR, 8 gathers in flight ----------------
__global__ __launch_bounds__(256) void agg_v2(const unsigned short* __restrict__ T,
        const int* __restrict__ esrc, const int* __restrict__ offs,
        const float* __restrict__ dinv, const float* __restrict__ bias,
        unsigned short* __restrict__ outh) {
    int node = blockIdx.x * 4 + (threadIdx.x >> 6);
    if (node >= NNODES) return;
    const int l = threadIdx.x & 63;
    const int half = l >> 5, sub = l & 31;
    const uint4* Tv = (const uint4*)T;   // row = 32 x uint4
    float a[8] = {0.f, 0.f, 0.f, 0.f, 0.f, 0.f, 0.f, 0.f};
    const int e0 = offs[node], e1 = offs[node + 1];
    int e = e0 + half;
    for (; e + 6 < e1; e += 8) {
        int s0 = esrc[e], s1 = esrc[e + 2], s2 = esrc[e + 4], s3 = esrc[e + 6];
        uint4 u0 = Tv[(size_t)s0 * 32 + sub];
        uint4 u1 = Tv[(size_t)s1 * 32 + sub];
        uint4 u2 = Tv[(size_t)s2 * 32 + sub];
        uint4 u3 = Tv[(size_t)s3 * 32 + sub];
        acc8(a, u0); acc8(a, u1); acc8(a, u2); acc8(a, u3);
    }
    for (; e < e1; e += 2) {
        int s0 = esrc[e];
        uint4 u0 = Tv[(size_t)s0 * 32 + sub];
        acc8(a, u0);
    }
#pragma unroll
    for (int j = 0; j < 8; ++j) a[j] += __shfl_xor(a[j], 32, 64);
    if (!half) {
        float di = dinv[node];
        float4 b0 = *(const float4*)(bias + sub * 8);
        float4 b1 = *(const float4*)(bias + sub * 8 + 4);
        float r0 = fmaxf(fmaf(a[0], di, b0.x), 0.f);
        float r1 = fmaxf(fmaf(a[1], di, b0.y), 0.f);
        float r2 = fmaxf(fmaf(a[2], di, b0.z), 0.f);
        float r3 = fmaxf(fmaf(a[3], di, b0.w), 0.f);
        float r4 = fmaxf(fmaf(a[4], di, b1.x), 0.f);
        float r5 = fmaxf(fmaf(a[5], di, b1.y), 0.f);
        float r6 = fmaxf(fmaf(a[6], di, b1.z), 0.f);
        float r7 = fmaxf(fmaf(a[7], di, b1.w), 0.f);
        uint4 o;
        o.x = (unsigned)f2h(r0) | ((unsigned)f2h(r1) << 16);
        o.y = (unsigned)f2h(r2) | ((unsigned)f2h(r3) << 16);
        o.z = (unsigned)f2h(r4) | ((unsigned)f2h(r5) << 16);
        o.w = (unsigned)f2h(r6) | ((unsigned)f2h(r7) << 16);
        ((uint4*)outh)[(size_t)node * 32 + sub] = o;
    }
}

// ---------------- layer-3 aggregation: 16-lane group per edge, 4 edges/iter ----------------
__global__ __launch_bounds__(256) void agg_out_v2(const unsigned short* __restrict__ T,
        const int* __restrict__ esrc, const int* __restrict__ offs,
        const float* __restrict__ dinv, const float* __restrict__ bias,
        float* __restrict__ out) {
    int node = blockIdx.x * 4 + (threadIdx.x >> 6);
    if (node >= NNODES) return;
    const int l = threadIdx.x & 63;
    const int g = l >> 4, sl = l & 15;
    const bool act = sl < 10;
    float a0 = 0.f, a1 = 0.f, a2 = 0.f, a3 = 0.f;
    const int e0 = offs[node], e1 = offs[node + 1];
    for (int e = e0 + g; e < e1; e += 4) {
        int s = esrc[e];
        if (act) {
            ushort4 u = *(const ushort4*)(T + (size_t)s * 40 + sl * 4);
            a0 += h2f(u.x); a1 += h2f(u.y); a2 += h2f(u.z); a3 += h2f(u.w);
        }
    }
    a0 += __shfl_xor(a0, 16, 64); a1 += __shfl_xor(a1, 16, 64);
    a2 += __shfl_xor(a2, 16, 64); a3 += __shfl_xor(a3, 16, 64);
    a0 += __shfl_xor(a0, 32, 64); a1 += __shfl_xor(a1, 32, 64);
    a2 += __shfl_xor(a2, 32, 64); a3 += __shfl_xor(a3, 32, 64);
    if (g == 0 && act) {
        float di = dinv[node];
        float4 bv = *(const float4*)(bias + sl * 4);
        float4 o = make_float4(fmaf(a0, di, bv.x), fmaf(a1, di, bv.y),
                               fmaf(a2, di, bv.z), fmaf(a3, di, bv.w));
        *(float4*)(out + (size_t)node * 40 + sl * 4) = o;
    }
}

extern "C" void kernel_launch(void* const* d_in, const int* in_sizes, int n_in,
                              void* d_out, int out_size, void* d_ws, size_t ws_size,
                              hipStream_t stream) {
    const float* x  = (const float*)d_in[0];
    const int*   ei = (const int*)d_in[1];
    const float* W1 = (const float*)d_in[2];
    const float* b1 = (const float*)d_in[3];
    const float* W2 = (const float*)d_in[4];
    const float* b2 = (const float*)d_in[5];
    const float* W3 = (const float*)d_in[6];
    const float* b3 = (const float*)d_in[7];
    float* out = (float*)d_out;

    char* ws = (char*)d_ws;
    size_t o = 0;
    unsigned short* tbA  = (unsigned short*)(ws + o); o += (size_t)MPAD * 256 * 2;   // gemm out (dinv-scaled)
    unsigned short* tbB  = (unsigned short*)(ws + o); o += (size_t)MPAD * 256 * 2;   // agg out (h, relu'd)
    unsigned short* tb40 = (unsigned short*)(ws + o); o += (size_t)NNODES * NCLS * 2;
    unsigned short* W1T  = (unsigned short*)(ws + o); o += 131072;
    unsigned short* W2T  = (unsigned short*)(ws + o); o += 131072;
    int2* bedge  = (int2*)(ws + o);  o += (size_t)NBUCK * BCAP * 8;   // 16 MB
    int* gbcnt   = (int*)(ws + o);   o += 2048;
    int* esrc    = (int*)(ws + o);   o += (size_t)(NEDGES + NNODES) * 4;
    int* cnt     = (int*)(ws + o);   o += 400128;
    int* offs    = (int*)(ws + o);   o += 400384;
    float* dinv  = (float*)(ws + o); o += 400384;   // MPAD entries, pad=0
    int* incl    = (int*)(ws + o);   o += 400128;
    int* blksum  = (int*)(ws + o);   o += 2048;
    int* blkoff  = (int*)(ws + o);   o += 2048;
    int* flag    = (int*)(ws + o);   o += 256;
    if (ws_size < o) return;

    hipMemsetAsync(gbcnt, 0, 2048, stream);
    hipMemsetAsync(tbB + (size_t)NNODES * 256, 0, (MPAD - NNODES) * 512, stream);  // tbB pad rows

    k_detect<<<1, 64, 0, stream>>>(ei, flag);
    k_bucket<<<NBLKB, 256, 0, stream>>>(ei, flag, gbcnt, bedge);
    k_cnt<<<NBUCK, 256, 0, stream>>>(gbcnt, bedge, cnt);
    k_dinv<<<(MPAD + 255) / 256, 256, 0, stream>>>(cnt, dinv);
    k_scan1<<<NBLK_SCAN, 256, 0, stream>>>(cnt, incl, blksum);
    k_scan2<<<1, 512, 0, stream>>>(blksum, blkoff);
    k_scan3<<<NBLK_SCAN, 256, 0, stream>>>(incl, blkoff, offs);
    k_self<<<NBLK_SCAN, 256, 0, stream>>>(offs, esrc);
    k_fill2<<<NBUCK, 256, 0, stream>>>(gbcnt, bedge, offs, esrc);

    k_wt<<<256, 256, 0, stream>>>(W1, W1T);
    k_wt<<<256, 256, 0, stream>>>(W2, W2T);

    dim3 gg(MPAD / 128, 2), b256(256);
    // layer 1 (A = fp32 x, read directly)
    gemm_core<true><<<gg, b256, 0, stream>>>(x, W1T, tbA, dinv);
    agg_v2<<<NNODES / 4, 256, 0, stream>>>(tbA, esrc, offs, dinv, b1, tbB);
    // layer 2
    gemm_core<false><<<gg, b256, 0, stream>>>(tbB, W2T, tbA, dinv);
    agg_v2<<<NNODES / 4, 256, 0, stream>>>(tbA, esrc, offs, dinv, b2, tbB);
    // layer 3
    gemm40_h16<<<(NNODES + 63) / 64, 256, 0, stream>>>(tbB, W3, tb40, NNODES, dinv);
    agg_out_v2<<<NNODES / 4, 256, 0, stream>>>(tb40, esrc, offs, dinv, b3, out);
}

// Round 6
// 492.228 us; speedup vs baseline: 2.8620x; 1.1071x over previous
//
#include <hip/hip_runtime.h>
#include <hip/hip_bf16.h>
#include <cstdint>
#include <cstddef>

#define NNODES 100000
#define NEDGES 1600000
#define NCLS 40
#define NBLK_SCAN 391   // ceil(100000/256)
#define NBUCK 391       // dst>>8 buckets (256 nodes each)
#define BCAP 5120       // bucket capacity (mean 4096, +16 sigma)
#define NBLKB 256
#define CHUNK 6250      // NEDGES / NBLKB exactly
#define MPAD 100096     // 782*128, zero-padded rows

typedef _Float16 f16;
typedef _Float16 f16x8 __attribute__((ext_vector_type(8)));
typedef float f32x4 __attribute__((ext_vector_type(4)));

__device__ inline float h2f(unsigned short u) {
    f16 h; __builtin_memcpy(&h, &u, 2); return (float)h;
}
__device__ inline unsigned short f2h(float f) {
    f16 h = (f16)f; unsigned short u; __builtin_memcpy(&u, &h, 2); return u;
}
__device__ inline void gload_lds16(const void* g, void* l) {
    __builtin_amdgcn_global_load_lds((const __attribute__((address_space(1))) unsigned int*)g,
                                     (__attribute__((address_space(3))) unsigned int*)l, 16, 0, 0);
}
// a_lo += (float)f16_lo(u); a_hi += (float)f16_hi(u)  — one v_fma_mix_f32 each (bit-exact cvt+fp32 add)
__device__ inline void fmix2(float& alo, float& ahi, unsigned u, float one) {
    asm("v_fma_mix_f32 %0, %1, %2, %0 op_sel:[0,0,0] op_sel_hi:[1,0,0]"
        : "+v"(alo) : "v"(u), "v"(one));
    asm("v_fma_mix_f32 %0, %1, %2, %0 op_sel:[1,0,0] op_sel_hi:[1,0,0]"
        : "+v"(ahi) : "v"(u), "v"(one));
}

// ---------------- edge dtype detect ----------------
__global__ void k_detect(const int* __restrict__ ei, int* __restrict__ flag) {
    if (threadIdx.x == 0 && blockIdx.x == 0) {
        int nz = 0;
        for (int i = 1; i < 256; i += 2) nz |= ei[i];
        *flag = (nz == 0) ? 1 : 0;   // 1 => int64 layout
    }
}

// ---------------- bucketed edge partition (LDS histogram + grouped writes) ----------------
__global__ __launch_bounds__(256) void k_bucket(const int* __restrict__ ei,
        const int* __restrict__ flag, int* __restrict__ gbcnt, int2* __restrict__ bedge) {
    __shared__ int lcnt[NBUCK], lbase[NBUCK], lcur[NBUCK];
    const int t = threadIdx.x;
    const int is64 = *flag;
    for (int i = t; i < NBUCK; i += 256) lcnt[i] = 0;
    __syncthreads();
    const int e0 = blockIdx.x * CHUNK;
    for (int i = t; i < CHUNK; i += 256) {
        int e = e0 + i;
        int d = is64 ? ei[2 * ((size_t)NEDGES + e)] : ei[NEDGES + e];
        atomicAdd(&lcnt[d >> 8], 1);
    }
    __syncthreads();
    for (int i = t; i < NBUCK; i += 256) {
        int c = lcnt[i];
        lbase[i] = c ? atomicAdd(&gbcnt[i], c) : 0;
        lcur[i] = 0;
    }
    __syncthreads();
    for (int i = t; i < CHUNK; i += 256) {
        int e = e0 + i;
        int s, d;
        if (is64) { s = ei[2 * (size_t)e]; d = ei[2 * ((size_t)NEDGES + e)]; }
        else      { s = ei[e];             d = ei[NEDGES + e]; }
        int b = d >> 8;
        int p = lbase[b] + atomicAdd(&lcur[b], 1);
        if (p < BCAP) bedge[(size_t)b * BCAP + p] = make_int2(s, d);
    }
}

// ---------------- per-bucket node-degree count ----------------
__global__ __launch_bounds__(256) void k_cnt(const int* __restrict__ gbcnt,
        const int2* __restrict__ bedge, int* __restrict__ cnt) {
    __shared__ int lc[256];
    const int t = threadIdx.x, b = blockIdx.x;
    lc[t] = 0;
    __syncthreads();
    const int ne = min(gbcnt[b], BCAP);
    const int2* be = bedge + (size_t)b * BCAP;
    for (int i = t; i < ne; i += 256)
        atomicAdd(&lc[be[i].y & 255], 1);
    __syncthreads();
    int node = b * 256 + t;
    if (node < NNODES) cnt[node] = lc[t];
}

// dinv over MPAD (pad rows -> 0)
__global__ __launch_bounds__(256) void k_dinv(const int* __restrict__ cnt, float* __restrict__ dinv) {
    int i = blockIdx.x * 256 + threadIdx.x;
    if (i < MPAD) dinv[i] = (i < NNODES) ? rsqrtf((float)(cnt[i] + 1)) : 0.f;
}

// ---------------- hierarchical scan over (cnt[i]+1)  (self-loop included) ----------------
__global__ __launch_bounds__(256) void k_scan1(const int* __restrict__ cnt,
        int* __restrict__ incl, int* __restrict__ blksum) {
    __shared__ int sm[256];
    const int t = threadIdx.x;
    int i = blockIdx.x * 256 + t;
    int v = (i < NNODES) ? (cnt[i] + 1) : 0;
    sm[t] = v;
    __syncthreads();
    for (int d = 1; d < 256; d <<= 1) {
        int x = (t >= d) ? sm[t - d] : 0;
        __syncthreads();
        sm[t] += x;
        __syncthreads();
    }
    if (i < NNODES) incl[i] = sm[t];
    if (t == 255) blksum[blockIdx.x] = sm[255];
}

__global__ __launch_bounds__(512) void k_scan2(const int* __restrict__ blksum, int* __restrict__ blkoff) {
    __shared__ int sm[512];
    const int t = threadIdx.x;
    int v = (t < NBLK_SCAN) ? blksum[t] : 0;
    sm[t] = v;
    __syncthreads();
    for (int d = 1; d < 512; d <<= 1) {
        int x = (t >= d) ? sm[t - d] : 0;
        __syncthreads();
        sm[t] += x;
        __syncthreads();
    }
    if (t < NBLK_SCAN) blkoff[t] = sm[t] - v;
}

__global__ __launch_bounds__(256) void k_scan3(const int* __restrict__ incl,
        const int* __restrict__ blkoff, int* __restrict__ offs) {
    int i = blockIdx.x * 256 + threadIdx.x;
    if (i < NNODES) offs[i + 1] = incl[i] + blkoff[blockIdx.x];
    if (i == 0) offs[0] = 0;
}

// self edge at slot 0 of each node's bucket
__global__ __launch_bounds__(256) void k_self(const int* __restrict__ offs, int* __restrict__ esrc) {
    int i = blockIdx.x * 256 + threadIdx.x;
    if (i < NNODES) esrc[offs[i]] = i;
}

// ---------------- per-bucket exact scatter (L2-local, block-exclusive region) ----------------
__global__ __launch_bounds__(256) void k_fill2(const int* __restrict__ gbcnt,
        const int2* __restrict__ bedge, const int* __restrict__ offs, int* __restrict__ esrc) {
    __shared__ int loff[256], lcur[256];
    const int t = threadIdx.x, b = blockIdx.x;
    int node = b * 256 + t;
    loff[t] = (node < NNODES) ? offs[node] : 0;
    lcur[t] = 0;
    __syncthreads();
    const int ne = min(gbcnt[b], BCAP);
    const int2* be = bedge + (size_t)b * BCAP;
    for (int i = t; i < ne; i += 256) {
        int2 sd = be[i];
        int li = sd.y & 255;
        int p = loff[li] + 1 + atomicAdd(&lcur[li], 1);   // +1: slot 0 is self-loop
        esrc[p] = sd.x;
    }
}

// ---------------- W[256][256] fp32 -> WT[n][k] fp16 ----------------
__global__ __launch_bounds__(256) void k_wt(const float* __restrict__ W, unsigned short* __restrict__ WT) {
    int k = blockIdx.x;
    int n = threadIdx.x;
    WT[n * 256 + k] = f2h(W[k * 256 + n]);
}

// W3[256][40] fp32 -> W3T[128][256] fp16 (rows 40..127 zero)
__global__ __launch_bounds__(256) void k_wt3(const float* __restrict__ W, unsigned short* __restrict__ WT) {
    int n = blockIdx.x;    // 0..127
    int k = threadIdx.x;   // 0..255
    WT[n * 256 + k] = (n < NCLS) ? f2h(W[k * NCLS + n]) : (unsigned short)0;
}

// ---------------- MFMA fp16 GEMM: C = dinv .* (A[MPAD,256] * W), W given as WT[n][k] ----------------
// 128x128 tile, BK=64, 4 waves, double-buffered LDS, XOR-swizzled slots.
// A32: A is fp32 (reg-staged, cvt fp16, write-late). NARROW: C has 40 cols (stride 80 B), grid.y==1.
template<bool A32, bool NARROW>
__global__ __launch_bounds__(256) void gemm_core(const void* __restrict__ Ap,
        const unsigned short* __restrict__ BT, unsigned short* __restrict__ C,
        const float* __restrict__ dinv) {
    __shared__ __align__(16) char lds[65536];   // 2 bufs x (A 16K + B 16K)
    const int t = threadIdx.x;
    const int w = t >> 6, l = t & 63;
    const int bm = blockIdx.x * 128;
    const int bn = blockIdx.y * 128;
    const int lr = l >> 3, ls = l & 7;
    const unsigned short* A16 = (const unsigned short*)Ap;
    const float* A32p = (const float*)Ap;

    auto stageB = [&](int buf, int k0) {
        char* base = lds + buf * 32768 + 16384;
#pragma unroll
        for (int i = 0; i < 4; ++i) {
            int r = w * 32 + i * 8 + lr;
            int sl = ls ^ (r & 7);
            const char* gB = (const char*)BT + (size_t)(bn + r) * 512 + (size_t)k0 * 2 + sl * 16;
            gload_lds16(gB, base + (w * 32 + i * 8) * 128);
        }
    };
    auto stageA16 = [&](int buf, int k0) {
        char* base = lds + buf * 32768;
#pragma unroll
        for (int i = 0; i < 4; ++i) {
            int r = w * 32 + i * 8 + lr;
            int sl = ls ^ (r & 7);
            const char* gA = (const char*)A16 + (size_t)(bm + r) * 512 + (size_t)k0 * 2 + sl * 16;
            gload_lds16(gA, base + (w * 32 + i * 8) * 128);
        }
    };
    float4 areg[8];
    auto issueA32 = [&](int k0) {
#pragma unroll
        for (int i = 0; i < 8; ++i) {
            int tt = i * 256 + t;
            int r = tt >> 4, q = tt & 15;
            float4 v = make_float4(0.f, 0.f, 0.f, 0.f);
            if (bm + r < NNODES) v = *(const float4*)(A32p + (size_t)(bm + r) * 256 + k0 + q * 4);
            areg[i] = v;
        }
    };
    auto writeA32 = [&](int buf) {
        char* base = lds + buf * 32768;
#pragma unroll
        for (int i = 0; i < 8; ++i) {
            int tt = i * 256 + t;
            int r = tt >> 4, q = tt & 15;
            f16 h4[4] = {(f16)areg[i].x, (f16)areg[i].y, (f16)areg[i].z, (f16)areg[i].w};
            char* dst = base + r * 128 + (((q >> 1) ^ (r & 7)) * 16) + (q & 1) * 8;
            __builtin_memcpy(dst, h4, 8);   // ds_write_b64
        }
    };

    f32x4 acc[4][4];
#pragma unroll
    for (int m = 0; m < 4; ++m)
#pragma unroll
        for (int n = 0; n < 4; ++n)
            acc[m][n] = (f32x4){0.f, 0.f, 0.f, 0.f};

    const int frow = l & 15, fk = l >> 4;
    const int r0w = (w >> 1) * 64, c0w = (w & 1) * 64;

    if constexpr (A32) { issueA32(0); } else { stageA16(0, 0); }
    stageB(0, 0);
    if constexpr (A32) { writeA32(0); }
    __syncthreads();
    for (int kt = 0; kt < 4; ++kt) {
        const int buf = kt & 1;
        if (kt < 3) {
            if constexpr (A32) { issueA32((kt + 1) * 64); } else { stageA16(buf ^ 1, (kt + 1) * 64); }
            stageB(buf ^ 1, (kt + 1) * 64);
        }
        const char* As = lds + buf * 32768;
        const char* Bs = As + 16384;
#pragma unroll
        for (int ks = 0; ks < 2; ++ks) {
            f16x8 af[4], bf[4];
#pragma unroll
            for (int m = 0; m < 4; ++m) {
                int ra = r0w + m * 16 + frow;
                af[m] = *(const f16x8*)(As + ra * 128 + (((ks * 4 + fk) ^ (ra & 7)) * 16));
            }
#pragma unroll
            for (int n = 0; n < 4; ++n) {
                int rb = c0w + n * 16 + frow;
                bf[n] = *(const f16x8*)(Bs + rb * 128 + (((ks * 4 + fk) ^ (rb & 7)) * 16));
            }
#pragma unroll
            for (int m = 0; m < 4; ++m)
#pragma unroll
                for (int n = 0; n < 4; ++n)
                    acc[m][n] = __builtin_amdgcn_mfma_f32_16x16x32_f16(af[m], bf[n], acc[m][n], 0, 0, 0);
        }
        if constexpr (A32) { if (kt < 3) writeA32(buf ^ 1); }
        __syncthreads();
    }

    // epilogue: scale rows by dinv, repack via LDS (stride 136 u16), coalesced 16B stores
    unsigned short* Cs = (unsigned short*)lds;   // [128][136]
    const int crow = (l >> 4) * 4, ccol = l & 15;
#pragma unroll
    for (int m = 0; m < 4; ++m) {
        float4 dv = *(const float4*)(dinv + bm + r0w + m * 16 + crow);
        float d4[4] = {dv.x, dv.y, dv.z, dv.w};
#pragma unroll
        for (int n = 0; n < 4; ++n)
#pragma unroll
            for (int r = 0; r < 4; ++r)
                Cs[(r0w + m * 16 + crow + r) * 136 + c0w + n * 16 + ccol] = f2h(acc[m][n][r] * d4[r]);
    }
    __syncthreads();
#pragma unroll
    for (int i = 0; i < 8; ++i) {
        int row = i * 16 + (t >> 4);
        int cs = t & 15;
        uint4 v = *(const uint4*)(Cs + row * 136 + cs * 8);
        if constexpr (NARROW) {
            if (cs < 5)
                *(uint4*)((char*)C + (size_t)(bm + row) * 80 + cs * 16) = v;
        } else {
            *(uint4*)((char*)C + (size_t)(bm + row) * 512 + bn * 2 + cs * 16) = v;
        }
    }
}

// ---------------- aggregation v3: register-cached indices, scalar row addr, fma_mix ----------------
// wave per node; whole wave per edge (64 lanes x 8 B = full 512 B row); no cross-lane reduce.
__global__ __launch_bounds__(256) void agg_v3(const unsigned short* __restrict__ T,
        const int* __restrict__ esrc, const int* __restrict__ offs,
        const float* __restrict__ dinv, const float* __restrict__ bias,
        unsigned short* __restrict__ outh) {
    int node = blockIdx.x * 4 + (threadIdx.x >> 6);
    if (node >= NNODES) return;
    const int l = threadIdx.x & 63;
    const float one = 1.0f;
    const int e0 = offs[node], e1 = offs[node + 1];
    const int ne = e1 - e0;
    const int myidx = esrc[e0 + min(l, ne - 1)];   // cache up to 64 indices, one per lane
    const char* Tb = (const char*)T;
    float a0 = 0.f, a1 = 0.f, a2 = 0.f, a3 = 0.f;
    const int nreg = min(ne, 64);
    int j = 0;
    for (; j + 8 <= nreg; j += 8) {
        uint2 u[8];
#pragma unroll
        for (int q = 0; q < 8; ++q) {
            int s = __builtin_amdgcn_readlane(myidx, j + q);
            u[q] = *(const uint2*)(Tb + (size_t)s * 512 + l * 8);
        }
#pragma unroll
        for (int q = 0; q < 8; ++q) {
            fmix2(a0, a1, u[q].x, one);
            fmix2(a2, a3, u[q].y, one);
        }
    }
    for (; j < nreg; ++j) {
        int s = __builtin_amdgcn_readlane(myidx, j);
        uint2 u = *(const uint2*)(Tb + (size_t)s * 512 + l * 8);
        fmix2(a0, a1, u.x, one);
        fmix2(a2, a3, u.y, one);
    }
    for (int e = e0 + 64; e < e1; ++e) {   // deg > 63 fallback (P ~ 0, must be correct)
        int s = esrc[e];
        uint2 u = *(const uint2*)(Tb + (size_t)s * 512 + l * 8);
        fmix2(a0, a1, u.x, one);
        fmix2(a2, a3, u.y, one);
    }
    float di = dinv[node];
    float4 bv = *(const float4*)(bias + l * 4);
    float r0 = fmaxf(fmaf(a0, di, bv.x), 0.f);
    float r1 = fmaxf(fmaf(a1, di, bv.y), 0.f);
    float r2 = fmaxf(fmaf(a2, di, bv.z), 0.f);
    float r3 = fmaxf(fmaf(a3, di, bv.w), 0.f);
    uint2 o;
    o.x = (unsigned)f2h(r0) | ((unsigned)f2h(r1) << 16);
    o.y = (unsigned)f2h(r2) | ((unsigned)f2h(r3) << 16);
    *(uint2*)(outh + (size_t)node * 256 + l * 4) = o;
}

// ---------------- layer-3 aggregation: register indices + fma_mix; 16-lane group per edge ----------------
__global__ __launch_bounds__(256) void agg_out_v3(const unsigned short* __restrict__ T,
        const int* __restrict__ esrc, const int* __restrict__ offs,
        const float* __restrict__ dinv, const float* __restrict__ bias,
        float* __restrict__ out) {
    int node = blockIdx.x * 4 + (threadIdx.x >> 6);
    if (node >= NNODES) return;
    const int l = threadIdx.x & 63;
    const int g = l >> 4, sl = l & 15;
    const bool act = sl < 10;
    const float one = 1.0f;
    const int e0 = offs[node], e1 = offs[node + 1];
    const int ne = e1 - e0;
    const int myidx = esrc[e0 + min(l, ne - 1)];
    const int nreg = min(ne, 64);
    const char* Tb = (const char*)T;
    float a0 = 0.f, a1 = 0.f, a2 = 0.f, a3 = 0.f;
    for (int j = 0; j < nreg; j += 4) {
        int jj = j + g;
        int s = __shfl(myidx, jj, 64);
        if (jj < nreg && act) {
            uint2 u = *(const uint2*)(Tb + (size_t)s * 80 + sl * 8);
            fmix2(a0, a1, u.x, one);
            fmix2(a2, a3, u.y, one);
        }
    }
    for (int e = e0 + 64 + g; e < e1; e += 4) {   // deg > 63 fallback
        int s = esrc[e];
        if (act) {
            uint2 u = *(const uint2*)(Tb + (size_t)s * 80 + sl * 8);
            fmix2(a0, a1, u.x, one);
            fmix2(a2, a3, u.y, one);
        }
    }
    a0 += __shfl_xor(a0, 16, 64); a1 += __shfl_xor(a1, 16, 64);
    a2 += __shfl_xor(a2, 16, 64); a3 += __shfl_xor(a3, 16, 64);
    a0 += __shfl_xor(a0, 32, 64); a1 += __shfl_xor(a1, 32, 64);
    a2 += __shfl_xor(a2, 32, 64); a3 += __shfl_xor(a3, 32, 64);
    if (g == 0 && act) {
        float di = dinv[node];
        float4 bv = *(const float4*)(bias + sl * 4);
        float4 o = make_float4(fmaf(a0, di, bv.x), fmaf(a1, di, bv.y),
                               fmaf(a2, di, bv.z), fmaf(a3, di, bv.w));
        *(float4*)(out + (size_t)node * 40 + sl * 4) = o;
    }
}

extern "C" void kernel_launch(void* const* d_in, const int* in_sizes, int n_in,
                              void* d_out, int out_size, void* d_ws, size_t ws_size,
                              hipStream_t stream) {
    const float* x  = (const float*)d_in[0];
    const int*   ei = (const int*)d_in[1];
    const float* W1 = (const float*)d_in[2];
    const float* b1 = (const float*)d_in[3];
    const float* W2 = (const float*)d_in[4];
    const float* b2 = (const float*)d_in[5];
    const float* W3 = (const float*)d_in[6];
    const float* b3 = (const float*)d_in[7];
    float* out = (float*)d_out;

    char* ws = (char*)d_ws;
    size_t o = 0;
    unsigned short* tbA  = (unsigned short*)(ws + o); o += (size_t)MPAD * 256 * 2;   // gemm out (dinv-scaled)
    unsigned short* tbB  = (unsigned short*)(ws + o); o += (size_t)MPAD * 256 * 2;   // agg out (h, relu'd)
    unsigned short* tb40 = (unsigned short*)(ws + o); o += (size_t)MPAD * NCLS * 2;  // layer-3 table
    unsigned short* W1T  = (unsigned short*)(ws + o); o += 131072;
    unsigned short* W2T  = (unsigned short*)(ws + o); o += 131072;
    unsigned short* W3T  = (unsigned short*)(ws + o); o += 65536;    // [128][256] padded
    int2* bedge  = (int2*)(ws + o);  o += (size_t)NBUCK * BCAP * 8;  // 16 MB
    int* gbcnt   = (int*)(ws + o);   o += 2048;
    int* esrc    = (int*)(ws + o);   o += (size_t)(NEDGES + NNODES) * 4;
    int* cnt     = (int*)(ws + o);   o += 400128;
    int* offs    = (int*)(ws + o);   o += 400384;
    float* dinv  = (float*)(ws + o); o += 400384;   // MPAD entries, pad=0
    int* incl    = (int*)(ws + o);   o += 400128;
    int* blksum  = (int*)(ws + o);   o += 2048;
    int* blkoff  = (int*)(ws + o);   o += 2048;
    int* flag    = (int*)(ws + o);   o += 256;
    if (ws_size < o) return;

    hipMemsetAsync(gbcnt, 0, 2048, stream);
    hipMemsetAsync(tbB + (size_t)NNODES * 256, 0, (MPAD - NNODES) * 512, stream);  // tbB pad rows

    k_detect<<<1, 64, 0, stream>>>(ei, flag);
    k_bucket<<<NBLKB, 256, 0, stream>>>(ei, flag, gbcnt, bedge);
    k_cnt<<<NBUCK, 256, 0, stream>>>(gbcnt, bedge, cnt);
    k_dinv<<<(MPAD + 255) / 256, 256, 0, stream>>>(cnt, dinv);
    k_scan1<<<NBLK_SCAN, 256, 0, stream>>>(cnt, incl, blksum);
    k_scan2<<<1, 512, 0, stream>>>(blksum, blkoff);
    k_scan3<<<NBLK_SCAN, 256, 0, stream>>>(incl, blkoff, offs);
    k_self<<<NBLK_SCAN, 256, 0, stream>>>(offs, esrc);
    k_fill2<<<NBUCK, 256, 0, stream>>>(gbcnt, bedge, offs, esrc);

    k_wt<<<256, 256, 0, stream>>>(W1, W1T);
    k_wt<<<256, 256, 0, stream>>>(W2, W2T);
    k_wt3<<<128, 256, 0, stream>>>(W3, W3T);

    dim3 gg(MPAD / 128, 2), b256(256);
    // layer 1 (A = fp32 x, read directly)
    gemm_core<true, false><<<gg, b256, 0, stream>>>(x, W1T, tbA, dinv);
    agg_v3<<<NNODES / 4, 256, 0, stream>>>(tbA, esrc, offs, dinv, b1, tbB);
    // layer 2
    gemm_core<false, false><<<gg, b256, 0, stream>>>(tbB, W2T, tbA, dinv);
    agg_v3<<<NNODES / 4, 256, 0, stream>>>(tbA, esrc, offs, dinv, b2, tbB);
    // layer 3 (MFMA, N padded to 128, narrow C-write)
    gemm_core<false, true><<<dim3(MPAD / 128, 1), b256, 0, stream>>>(tbB, W3T, tb40, dinv);
    agg_out_v3<<<NNODES / 4, 256, 0, stream>>>(tb40, esrc, offs, dinv, b3, out);
}